// Round 14
// baseline (507.054 us; speedup 1.0000x reference)
//
#include <hip/hip_runtime.h>
#include <hip/hip_bf16.h>
#include <math.h>
#include <stdint.h>

#define NEG_INF_F (-3.4028234663852886e38f)

typedef __bf16 bf16_t;
typedef __bf16 bf16x8 __attribute__((ext_vector_type(8)));
typedef float f32x4 __attribute__((ext_vector_type(4)));
typedef float f32x16 __attribute__((ext_vector_type(16)));
typedef int i32x4 __attribute__((ext_vector_type(4)));
typedef int i32x16 __attribute__((ext_vector_type(16)));
typedef int8_t c8x4 __attribute__((ext_vector_type(4)));

static constexpr int Bb = 2, Ss = 1024, Hid = 4096, Nh = 32, Dh = 128;
static constexpr int Mr = Bb * Ss;   // 2048 token rows
static constexpr int Bh = Bb * Nh;   // 64 (batch*heads)

__device__ __forceinline__ void gload_lds16(const void* g, void* l) {
  __builtin_amdgcn_global_load_lds((const __attribute__((address_space(1))) void*)g,
                                   (__attribute__((address_space(3))) void*)l, 16, 0, 0);
}

__device__ __forceinline__ float wred_max(float v) {
#pragma unroll
  for (int off = 32; off > 0; off >>= 1) v = fmaxf(v, __shfl_xor(v, off));
  return v;
}

__device__ __forceinline__ unsigned pkbf(float a, float b) {
  unsigned short ua = __builtin_bit_cast(unsigned short, (bf16_t)a);
  unsigned short ub = __builtin_bit_cast(unsigned short, (bf16_t)b);
  return (unsigned)ua | ((unsigned)ub << 16);
}

// ---------------- RoPE cos/sin tables [S][64] ----------------
__global__ void rope_table_kernel(float* __restrict__ ctab, float* __restrict__ stab) {
  int i = blockIdx.x * 256 + threadIdx.x;   // 0 .. S*64-1
  int srow = i >> 6, d = i & 63;
  float invf = (float)pow(10000.0, -((double)(2 * d) / (double)Dh));
  float ang = (float)srow * invf;           // f32 mul like numpy outer()
  ctab[i] = (float)cos((double)ang);
  stab[i] = (float)sin((double)ang);
}

// ------------- per-row symmetric fake-quant: int8 codes + f32 scale -------------
__device__ __forceinline__ void quant_row_body(
    const float* __restrict__ x, int8_t* __restrict__ o, float* __restrict__ scale,
    int row, int ncols, float qmax, float clo, float chi)
{
  const int tid = threadIdx.x;
  const float4* x4 = (const float4*)x;
  const int n4 = ncols >> 2;
  float m = 0.f;
  for (int i = tid; i < n4; i += 256) {
    float4 v = x4[i];
    m = fmaxf(m, fmaxf(fmaxf(fabsf(v.x), fabsf(v.y)), fmaxf(fabsf(v.z), fabsf(v.w))));
  }
  m = wred_max(m);
  __shared__ float red[4];
  if ((tid & 63) == 0) red[tid >> 6] = m;
  __syncthreads();
  m = fmaxf(fmaxf(red[0], red[1]), fmaxf(red[2], red[3]));
  const float s = fmaxf(m / qmax, 1e-8f);
  if (tid == 0) scale[row] = s;
  c8x4* o4 = (c8x4*)o;
  for (int i = tid; i < n4; i += 256) {
    float4 v = x4[i];
    c8x4 r;
    r[0] = (int8_t)(int)fminf(fmaxf(rintf(v.x / s), clo), chi);
    r[1] = (int8_t)(int)fminf(fmaxf(rintf(v.y / s), clo), chi);
    r[2] = (int8_t)(int)fminf(fmaxf(rintf(v.z / s), clo), chi);
    r[3] = (int8_t)(int)fminf(fmaxf(rintf(v.w / s), clo), chi);
    o4[i] = r;
  }
}

__global__ __launch_bounds__(256) void quant_rows_kernel(
    const float* __restrict__ in, int8_t* __restrict__ outq,
    float* __restrict__ scale, int ncols, float qmax, float clo, float chi)
{
  const int row = blockIdx.x;
  quant_row_body(in + (size_t)row * ncols, outq + (size_t)row * ncols, scale,
                 row, ncols, qmax, clo, chi);
}

// 4 weights in one early launch (w4 quant): sel = id>>12, row = id&4095
__global__ __launch_bounds__(256) void quant_w4_kernel(
    const float* __restrict__ w0, const float* __restrict__ w1,
    const float* __restrict__ w2, const float* __restrict__ w3,
    int8_t* __restrict__ o0, int8_t* __restrict__ o1,
    int8_t* __restrict__ o2, int8_t* __restrict__ o3,
    float* __restrict__ s0, float* __restrict__ s1,
    float* __restrict__ s2, float* __restrict__ s3)
{
  const int sel = blockIdx.x >> 12, row = blockIdx.x & 4095;
  const float* in = sel == 0 ? w0 : (sel == 1 ? w1 : (sel == 2 ? w2 : w3));
  int8_t* o = sel == 0 ? o0 : (sel == 1 ? o1 : (sel == 2 ? o2 : o3));
  float* sc = sel == 0 ? s0 : (sel == 1 ? s1 : (sel == 2 ? s2 : s3));
  quant_row_body(in + (size_t)row * Hid, o + (size_t)row * Hid, sc, row, Hid,
                 7.f, -8.f, 7.f);
}

// ===== QKV K-loop: BM=256 x BN=128, BK=64, counted-vmcnt double-buffer =====
// Per tile: A 256x64 (16KB, 4 issues) + B 128x64 (8KB, 2 issues) = 6 loads/thread.
// 2 tiles in flight (12 loads); vmcnt(6) waits only the current tile; raw barriers.
// Bank swizzle (verified R9/R10): source chunk ((tid&3)^((tid>>3)&3)), read chunk
// (kg4^((l15>>1)&3)) -> 2-way aliasing (free).
#define QKV_WAITBAR(N)                                                                \
  asm volatile("s_waitcnt vmcnt(" #N ")" ::: "memory");                               \
  __builtin_amdgcn_sched_barrier(0);                                                  \
  __builtin_amdgcn_s_barrier();                                                       \
  __builtin_amdgcn_sched_barrier(0);

#define QKV_BARONLY                                                                   \
  __builtin_amdgcn_sched_barrier(0);                                                  \
  __builtin_amdgcn_s_barrier();                                                       \
  __builtin_amdgcn_sched_barrier(0);

#define QKV_STAGE(koff, Abuf, Bbuf)                                                   \
  _Pragma("unroll")                                                                   \
  for (int r = 0; r < 4; ++r)                                                         \
    gload_lds16(gA + (koff) + (size_t)r * 64 * K, (Abuf) + r * 4096 + wid * 1024);    \
  _Pragma("unroll")                                                                   \
  for (int r = 0; r < 2; ++r)                                                         \
    gload_lds16(gB + (koff) + (size_t)r * 64 * K, (Bbuf) + r * 4096 + wid * 1024);

#define QKV_PHASE(Abuf, Bbuf)                                                         \
  {                                                                                   \
    i32x4 bw[4];                                                                      \
    _Pragma("unroll")                                                                 \
    for (int f = 0; f < 4; ++f)                                                       \
      bw[f] = *(const i32x4*)&(Bbuf)[(f * 32 + wn * 16 + l15) * 64 + ck];             \
    _Pragma("unroll")                                                                 \
    for (int fm = 0; fm < 8; ++fm) {                                                  \
      i32x4 af = *(const i32x4*)&(Abuf)[(wm * 128 + fm * 16 + l15) * 64 + ck];        \
      _Pragma("unroll")                                                               \
      for (int fn = 0; fn < 4; ++fn)                                                  \
        acc[fm][fn] = __builtin_amdgcn_mfma_i32_16x16x64_i8(af, bw[fn],               \
                                                            acc[fm][fn], 0, 0, 0);   \
    }                                                                                 \
  }

// ================= fused QKV i8 GEMM (256x128 tile), fused epilogues =================
__global__ __launch_bounds__(256) void qkv_gemm_kernel(
    const int8_t* __restrict__ A, const float* __restrict__ sA,
    const int8_t* __restrict__ wqz, const int8_t* __restrict__ wkz, const int8_t* __restrict__ wvz,
    const float* __restrict__ swq, const float* __restrict__ swk, const float* __restrict__ swv,
    int8_t* __restrict__ qqb, float* __restrict__ Fq,
    int8_t* __restrict__ kqb, float* __restrict__ Fk,
    bf16_t* __restrict__ vdq, float* __restrict__ a2vp,
    const float* __restrict__ ctab, const float* __restrict__ stab)
{
  __shared__ __align__(16) char smem[49152];
  // pipeline buffers (dead after K-loop; epilogue unions into this space)
  int8_t* A0 = (int8_t*)smem;             // 16KB
  int8_t* B0 = (int8_t*)smem + 16384;     // 8KB
  int8_t* A1 = (int8_t*)smem + 24576;     // 16KB
  int8_t* B1 = (int8_t*)smem + 40960;     // 8KB
  float (*s_red)[256][3] = (float (*)[256][3])smem;          // 6KB   (epilogue)
  bf16_t* svt = (bf16_t*)(smem + 8192);                      // 34.8KB (V epilogue)

  const int tid = threadIdx.x, lane = tid & 63, wid = tid >> 6;
  const int id = blockIdx.x;                 // 768 blocks, 8 XCDs, 12 n-panels each
  const int xcd = id & 7, within = id >> 3;  // within 0..95
  const int nIdx = xcd * 12 + (within >> 3); // 0..95
  const int mIdx = within & 7;               // 0..7
  const int wsel = nIdx >> 5, head = nIdx & 31;
  const int bm = mIdx * 256, bn = head * 128;
  const int8_t* W = wsel == 0 ? wqz : (wsel == 1 ? wkz : wvz);
  const float* sW = wsel == 0 ? swq : (wsel == 1 ? swk : swv);
  constexpr int K = Hid;

  const int wm = wid >> 1, wn = wid & 1;
  const int l15 = lane & 15, kg4 = lane >> 4;
  const int ck = (kg4 ^ ((l15 >> 1) & 3)) * 16;

  const int strow = tid >> 2;
  const int schunk = ((tid & 3) ^ ((tid >> 3) & 3)) * 16;
  const int8_t* gA = A + (size_t)(bm + strow) * K + schunk;
  const int8_t* gB = W + (size_t)(bn + strow) * K + schunk;

  i32x4 acc[8][4] = {};
  QKV_STAGE(0, A0, B0)
  QKV_STAGE(64, A1, B1)
  for (int k0 = 0; k0 + 256 <= K; k0 += 128) {
    QKV_WAITBAR(6)
    QKV_PHASE(A0, B0)
    QKV_BARONLY
    QKV_STAGE(k0 + 128, A0, B0)
    QKV_WAITBAR(6)
    QKV_PHASE(A1, B1)
    QKV_BARONLY
    QKV_STAGE(k0 + 192, A1, B1)
  }
  QKV_WAITBAR(6)
  QKV_PHASE(A0, B0)
  QKV_BARONLY
  QKV_WAITBAR(0)
  QKV_PHASE(A1, B1)

  // ---- epilogue: scales, rope, per-row quant, stores ----
  float sav[8][4], swv_[4];
#pragma unroll
  for (int fm = 0; fm < 8; ++fm)
#pragma unroll
    for (int j = 0; j < 4; ++j) sav[fm][j] = sA[bm + wm * 128 + fm * 16 + kg4 * 4 + j];
#pragma unroll
  for (int fn = 0; fn < 4; ++fn) swv_[fn] = sW[bn + fn * 32 + wn * 16 + l15];

  // w: acc -> f32 val -> rope'd -> int8 codes (in place, lifetimes sequential)
  float w[8][4][4];
#pragma unroll
  for (int fm = 0; fm < 8; ++fm)
#pragma unroll
    for (int fn = 0; fn < 4; ++fn)
#pragma unroll
      for (int j = 0; j < 4; ++j)
        w[fm][fn][j] = (float)acc[fm][fn][j] * sav[fm][j] * swv_[fn];

  const int b = bm >> 10;
  const int bh = b * Nh + head;
  if (wsel != 2) {   // Q or K: rope in place
    const int dmA = wn * 16 + l15, dmB = 32 + wn * 16 + l15;
#pragma unroll
    for (int fm = 0; fm < 8; ++fm)
#pragma unroll
      for (int j = 0; j < 4; ++j) {
        const int srow = (bm + wm * 128 + fm * 16 + kg4 * 4 + j) & (Ss - 1);
        const float cA = ctab[srow * 64 + dmA], cB = ctab[srow * 64 + dmB];
        const float sA_ = stab[srow * 64 + dmA], sB_ = stab[srow * 64 + dmB];
        const float a0 = w[fm][0][j], a1 = w[fm][1][j];
        const float a2 = w[fm][2][j], a3 = w[fm][3][j];
        w[fm][0][j] = __fsub_rn(__fmul_rn(a0, cA), __fmul_rn(a2, sA_));
        w[fm][1][j] = __fsub_rn(__fmul_rn(a1, cB), __fmul_rn(a3, sB_));
        w[fm][2][j] = __fadd_rn(__fmul_rn(a2, cA), __fmul_rn(a0, sA_));
        w[fm][3][j] = __fadd_rn(__fmul_rn(a3, cB), __fmul_rn(a1, sB_));
      }
  }
  // per-row (ma, n2): wave-half partial then cross-wn via s_red
  float ma_[8][4], n2_[8][4];
#pragma unroll
  for (int fm = 0; fm < 8; ++fm)
#pragma unroll
    for (int j = 0; j < 4; ++j) {
      float ma = 0.f, n2 = 0.f;
#pragma unroll
      for (int fn = 0; fn < 4; ++fn) {
        const float x = w[fm][fn][j];
        ma = fmaxf(ma, fabsf(x));
        n2 += x * x;
      }
#pragma unroll
      for (int off = 1; off < 16; off <<= 1) {
        ma = fmaxf(ma, __shfl_xor(ma, off));
        n2 += __shfl_xor(n2, off);
      }
      ma_[fm][j] = ma;
      n2_[fm][j] = n2;
    }
  if (l15 == 0) {
#pragma unroll
    for (int fm = 0; fm < 8; ++fm)
#pragma unroll
      for (int j = 0; j < 4; ++j) {
        const int rl = wm * 128 + fm * 16 + kg4 * 4 + j;
        s_red[wn][rl][0] = ma_[fm][j];
        s_red[wn][rl][1] = n2_[fm][j];
      }
  }
  __syncthreads();
  float svl[8][4], n2c[8][4], nq2_[8][4];
#pragma unroll
  for (int fm = 0; fm < 8; ++fm)
#pragma unroll
    for (int j = 0; j < 4; ++j) {
      const int rl = wm * 128 + fm * 16 + kg4 * 4 + j;
      const float ma = fmaxf(ma_[fm][j], s_red[wn ^ 1][rl][0]);
      const float n2 = n2_[fm][j] + s_red[wn ^ 1][rl][1];
      const float s = fmaxf(ma / 127.0f, 1e-8f);
      float nq2 = 0.f;
#pragma unroll
      for (int fn = 0; fn < 4; ++fn) {
        const float q = fminf(fmaxf(rintf(w[fm][fn][j] / s), -128.f), 127.f);
        w[fm][fn][j] = q;          // codes, in place
        nq2 += q * q;
      }
#pragma unroll
      for (int off = 1; off < 16; off <<= 1) nq2 += __shfl_xor(nq2, off);
      svl[fm][j] = s;
      n2c[fm][j] = n2;
      nq2_[fm][j] = nq2;
    }
  __syncthreads();
  if (l15 == 0) {
#pragma unroll
    for (int fm = 0; fm < 8; ++fm)
#pragma unroll
      for (int j = 0; j < 4; ++j)
        s_red[wn][wm * 128 + fm * 16 + kg4 * 4 + j][2] = nq2_[fm][j];
  }
  __syncthreads();

  if (wsel != 2) {
    int8_t* outq = (wsel == 0) ? qqb : kqb;
    float* Ff = (wsel == 0) ? Fq : Fk;
#pragma unroll
    for (int fm = 0; fm < 8; ++fm)
#pragma unroll
      for (int j = 0; j < 4; ++j) {
        const int rl = wm * 128 + fm * 16 + kg4 * 4 + j;
        const int stok = (bm + rl) & (Ss - 1);
        const size_t rowBase = ((size_t)bh * Ss + stok) * Dh;
#pragma unroll
        for (int fn = 0; fn < 4; ++fn)
          outq[rowBase + fn * 32 + wn * 16 + l15] = (int8_t)(int)w[fm][fn][j];
        if (wn == 0 && l15 == 0) {
          const float nq2 = nq2_[fm][j] + s_red[1][rl][2];
          Ff[(size_t)bh * Ss + stok] = sqrtf(n2c[fm][j] / nq2) * 0.2973017787506803f;
        }
      }
  } else {
    // a2v factors
    if (wn == 0 && l15 == 0) {
#pragma unroll
      for (int fm = 0; fm < 8; ++fm)
#pragma unroll
        for (int j = 0; j < 4; ++j) {
          const int rl = wm * 128 + fm * 16 + kg4 * 4 + j;
          const float nq2 = nq2_[fm][j] + s_red[1][rl][2];
          a2vp[(size_t)bh * Ss + ((bm + rl) & (Ss - 1))] =
              svl[fm][j] * sqrtf(nq2) / sqrtf(n2c[fm][j]);
        }
    }
    // dequant-V transposed store via LDS, two 128-token halves (wave's wm = half)
    for (int half = 0; half < 2; ++half) {
      if (wm == half) {
#pragma unroll
        for (int fm = 0; fm < 8; ++fm)
#pragma unroll
          for (int j = 0; j < 4; ++j) {
            const int t = fm * 16 + kg4 * 4 + j;   // 0..127 within half
#pragma unroll
            for (int fn = 0; fn < 4; ++fn) {
              const int d = fn * 32 + wn * 16 + l15;
              svt[d * 136 + t] = (bf16_t)(w[fm][fn][j] * svl[fm][j]);
            }
          }
      }
      __syncthreads();
      const int d = tid >> 1, toff = (tid & 1) * 64;
      const int s0h = (bm & (Ss - 1)) + half * 128;
      const bf16_t* src = svt + d * 136 + toff;
      bf16_t* dst = vdq + ((size_t)bh * Dh + d) * Ss + s0h + toff;
#pragma unroll
      for (int k = 0; k < 8; ++k) {
        bf16x8 tv;
#pragma unroll
        for (int e = 0; e < 8; ++e) tv[e] = src[k * 8 + e];
        *(bf16x8*)(dst + k * 8) = tv;
      }
      __syncthreads();
    }
  }
}

// ===== output i8 GEMM: BK=128 single-buffer 2-barrier core (best at 512 blocks) =====
__global__ __launch_bounds__(256) void gemm0_kernel(
    const int8_t* __restrict__ A, const float* __restrict__ sA,
    const int8_t* __restrict__ W, const float* __restrict__ sW,
    float* __restrict__ out, int M, int N, int K)
{
  __shared__ __align__(16) int8_t As[128 * 128];
  __shared__ __align__(16) int8_t Bs[128 * 128];
  const int tid = threadIdx.x, lane = tid & 63, wid = tid >> 6;
  const int id = blockIdx.x;
  const int xcd = id & 7, within = id >> 3;
  const int nIdx = xcd * 4 + (within >> 4);
  const int mIdx = within & 15;
  const int bm = mIdx * 128, bn = nIdx * 128;
  const int wm = wid >> 1, wn = wid & 1;
  const int l15 = lane & 15, kg4 = lane >> 4;

  const int strow = wid * 8 + (lane >> 3);
  const int schunk = ((lane & 7) ^ (lane >> 3)) * 16;
  const int8_t* gA = A + (size_t)(bm + strow) * K + schunk;
  const int8_t* gB = W + (size_t)(bn + strow) * K + schunk;

  i32x4 acc[4][4] = {};
  for (int k0 = 0; k0 < K; k0 += 128) {
    if (k0) __syncthreads();
#pragma unroll
    for (int r = 0; r < 4; ++r) {
      gload_lds16(gA + k0 + (size_t)r * 32 * K, As + r * 4096 + wid * 1024);
      gload_lds16(gB + k0 + (size_t)r * 32 * K, Bs + r * 4096 + wid * 1024);
    }
    __syncthreads();
#pragma unroll
    for (int g = 0; g < 2; ++g) {
      i32x4 af[4], bw[4];
#pragma unroll
      for (int f = 0; f < 4; ++f) {
        const int ca = (((g << 2) | kg4) ^ (l15 & 7)) * 16;
        af[f] = *(const i32x4*)&As[(wm * 64 + f * 16 + l15) * 128 + ca];
        bw[f] = *(const i32x4*)&Bs[(f * 32 + wn * 16 + l15) * 128 + ca];
      }
#pragma unroll
      for (int fm = 0; fm < 4; ++fm)
#pragma unroll
        for (int fn = 0; fn < 4; ++fn)
          acc[fm][fn] = __builtin_amdgcn_mfma_i32_16x16x64_i8(af[fm], bw[fn], acc[fm][fn], 0, 0, 0);
    }
  }
#pragma unroll
  for (int fm = 0; fm < 4; ++fm) {
#pragma unroll
    for (int j = 0; j < 4; ++j) {
      const int row = bm + wm * 64 + fm * 16 + kg4 * 4 + j;
      const float sa = sA[row];
#pragma unroll
      for (int fn = 0; fn < 4; ++fn) {
        const int col = bn + fn * 32 + wn * 16 + l15;
        out[(size_t)row * N + col] = (float)acc[fm][fn][j] * sa * sW[col];
      }
    }
  }
}

// ------------- fused attention: 1 wave per 32 q-rows, no LDS, no barriers -------------
// grid (Bh, 32); unit u = 31 - blockIdx.y (heavy-first); q0 = u*32; nt = u+1 k-tiles.
#define KR(r) (((r) & 3) + 8 * ((r) >> 2) + 4 * hi)
__global__ __launch_bounds__(64, 2) void attn_kernel(
    const int8_t* __restrict__ qq, const int8_t* __restrict__ kq,
    const bf16_t* __restrict__ vdqt,
    const float* __restrict__ Fq, const float* __restrict__ Fk,
    const float* __restrict__ A2v, float* __restrict__ oattn)
{
  const int bh = blockIdx.x, b = bh >> 5, h = bh & 31;
  const int lane = threadIdx.x & 63;
  const int l31 = lane & 31, hi = lane >> 5;
  const int u = 31 - (int)blockIdx.y;
  const int q0 = u * 32;
  const int nt = u + 1;
  const size_t bhS = (size_t)bh * Ss;

  const int8_t* qrow = qq + (bhS + q0 + l31) * Dh + hi * 16;
  i32x4 qf[4];
#pragma unroll
  for (int c = 0; c < 4; ++c) qf[c] = *(const i32x4*)(qrow + c * 32);
  const float fq = Fq[bhS + q0 + l31];
  const int qcol = q0 + l31;

  float m = NEG_INF_F;
  int t = 0;
  for (; t + 1 < nt; t += 2) {
    const int kb0 = t * 32, kb1 = kb0 + 32;
    const int8_t* kr0 = kq + (bhS + kb0 + l31) * Dh + hi * 16;
    const int8_t* kr1 = kq + (bhS + kb1 + l31) * Dh + hi * 16;
    i32x16 ca = {}, cb = {}, da = {}, db = {};
    ca = __builtin_amdgcn_mfma_i32_32x32x32_i8(*(const i32x4*)(kr0),      qf[0], ca, 0, 0, 0);
    cb = __builtin_amdgcn_mfma_i32_32x32x32_i8(*(const i32x4*)(kr0 + 64), qf[2], cb, 0, 0, 0);
    da = __builtin_amdgcn_mfma_i32_32x32x32_i8(*(const i32x4*)(kr1),      qf[0], da, 0, 0, 0);
    db = __builtin_amdgcn_mfma_i32_32x32x32_i8(*(const i32x4*)(kr1 + 64), qf[2], db, 0, 0, 0);
    ca = __builtin_amdgcn_mfma_i32_32x32x32_i8(*(const i32x4*)(kr0 + 32), qf[1], ca, 0, 0, 0);
    cb = __builtin_amdgcn_mfma_i32_32x32x32_i8(*(const i32x4*)(kr0 + 96), qf[3], cb, 0, 0, 0);
    da = __builtin_amdgcn_mfma_i32_32x32x32_i8(*(const i32x4*)(kr1 + 32), qf[1], da, 0, 0, 0);
    db = __builtin_amdgcn_mfma_i32_32x32x32_i8(*(const i32x4*)(kr1 + 96), qf[3], db, 0, 0, 0);
    float4 fk40[4], fk41[4];
#pragma unroll
    for (int g = 0; g < 4; ++g) fk40[g] = *(const float4*)&Fk[bhS + kb0 + g * 8 + 4 * hi];
#pragma unroll
    for (int g = 0; g < 4; ++g) fk41[g] = *(const float4*)&Fk[bhS + kb1 + g * 8 + 4 * hi];
    const bool diag1 = (t + 1 == nt - 1);
#pragma unroll
    for (int r = 0; r < 16; ++r) {
      m = fmaxf(m, (float)(ca[r] + cb[r]) * fq * ((const float*)&fk40[r >> 2])[r & 3]);
      const float v1 = (float)(da[r] + db[r]) * fq * ((const float*)&fk41[r >> 2])[r & 3];
      if (!diag1 || (kb1 + KR(r) <= qcol)) m = fmaxf(m, v1);
    }
  }
  if (t < nt) {
    const int kb = t * 32;
    const int8_t* krow = kq + (bhS + kb + l31) * Dh + hi * 16;
    i32x16 ca = {}, cb = {};
    ca = __builtin_amdgcn_mfma_i32_32x32x32_i8(*(const i32x4*)(krow),      qf[0], ca, 0, 0, 0);
    cb = __builtin_amdgcn_mfma_i32_32x32x32_i8(*(const i32x4*)(krow + 64), qf[2], cb, 0, 0, 0);
    ca = __builtin_amdgcn_mfma_i32_32x32x32_i8(*(const i32x4*)(krow + 32), qf[1], ca, 0, 0, 0);
    cb = __builtin_amdgcn_mfma_i32_32x32x32_i8(*(const i32x4*)(krow + 96), qf[3], cb, 0, 0, 0);
    float4 fk4[4];
#pragma unroll
    for (int g = 0; g < 4; ++g) fk4[g] = *(const float4*)&Fk[bhS + kb + g * 8 + 4 * hi];
#pragma unroll
    for (int r = 0; r < 16; ++r) {
      const float v = (float)(ca[r] + cb[r]) * fq * ((const float*)&fk4[r >> 2])[r & 3];
      if (kb + KR(r) <= qcol) m = fmaxf(m, v);
    }
  }
  m = fmaxf(m, __shfl_xor(m, 32));

  float z = 0.f;
  f32x16 oacc[4] = {};
  for (int tt = 0; tt < nt; ++tt) {
    const int kb = tt * 32;
    const int8_t* krow = kq + (bhS + kb + l31) * Dh + hi * 16;
    i32x16 ca = {}, cb = {};
    ca = __builtin_amdgcn_mfma_i32_32x32x32_i8(*(const i32x4*)(krow),      qf[0], ca, 0, 0, 0);
    cb = __builtin_amdgcn_mfma_i32_32x32x32_i8(*(const i32x4*)(krow + 64), qf[2], cb, 0, 0, 0);
    ca = __builtin_amdgcn_mfma_i32_32x32x32_i8(*(const i32x4*)(krow + 32), qf[1], ca, 0, 0, 0);
    cb = __builtin_amdgcn_mfma_i32_32x32x32_i8(*(const i32x4*)(krow + 96), qf[3], cb, 0, 0, 0);
    float4 fk4[4];
#pragma unroll
    for (int g = 0; g < 4; ++g) fk4[g] = *(const float4*)&Fk[bhS + kb + g * 8 + 4 * hi];
    float p[16];
    const bool diag = (tt == nt - 1);
#pragma unroll
    for (int r = 0; r < 16; ++r) {
      float v = (float)(ca[r] + cb[r]) * fq * ((const float*)&fk4[r >> 2])[r & 3];
      if (diag && (kb + KR(r) > qcol)) v = NEG_INF_F;
      const float e = __expf(v - m);
      z += e;
      p[r] = rintf(127.0f * e);
    }
#pragma unroll
    for (int s = 0; s < 2; ++s) {
      const int rs = s * 8;
      unsigned k0 = pkbf(p[rs + 0], p[rs + 1]);
      unsigned k1 = pkbf(p[rs + 2], p[rs + 3]);
      unsigned k2 = pkbf(p[rs + 4], p[rs + 5]);
      unsigned k3 = pkbf(p[rs + 6], p[rs + 7]);
      unsigned sx0 = __shfl_xor(k0, 32);
      unsigned sx1 = __shfl_xor(k1, 32);
      unsigned sx2 = __shfl_xor(k2, 32);
      unsigned sx3 = __shfl_xor(k3, 32);
      uint4 ww;
      ww.x = hi ? sx2 : k0;
      ww.y = hi ? sx3 : k1;
      ww.z = hi ? k2 : sx0;
      ww.w = hi ? k3 : sx1;
      const bf16x8 af = __builtin_bit_cast(bf16x8, ww);
      const int kg2 = kb + s * 16 + hi * 8;
#pragma unroll
      for (int dt = 0; dt < 4; ++dt) {
        const bf16x8 vf = *(const bf16x8*)(vdqt + ((size_t)bh * Dh + dt * 32 + l31) * Ss + kg2);
        oacc[dt] = __builtin_amdgcn_mfma_f32_32x32x16_bf16(af, vf, oacc[dt], 0, 0, 0);
      }
    }
  }
  z += __shfl_xor(z, 32);
  const float osc = (1.0f / z) / 127.0f / A2v[bhS + q0 + l31];
#pragma unroll
  for (int dt = 0; dt < 4; ++dt) {
#pragma unroll
    for (int r = 0; r < 16; ++r) {
      const int q = q0 + KR(r);
      const float oscr = __shfl(osc, KR(r));
      oattn[((size_t)b * Ss + q) * Hid + h * Dh + dt * 32 + l31] = oacc[dt][r] * oscr;
    }
  }
}

extern "C" void kernel_launch(void* const* d_in, const int* in_sizes, int n_in,
                              void* d_out, int out_size, void* d_ws, size_t ws_size,
                              hipStream_t stream)
{
  const float* hidden = (const float*)d_in[0];
  const float* wq = (const float*)d_in[1];
  const float* wk = (const float*)d_in[2];
  const float* wv = (const float*)d_in[3];
  const float* wo = (const float*)d_in[4];
  float* out = (float*)d_out;

  char* p = (char*)d_ws;
  auto alloc = [&](size_t bytes) -> char* {
    char* r = p; p += (bytes + 255) & ~(size_t)255; return r;
  };
  int8_t* xq   = (int8_t*)alloc((size_t)Mr * Hid);       // later reused for oq
  int8_t* wb0  = (int8_t*)alloc((size_t)Hid * Hid);      // wq codes
  int8_t* wb1  = (int8_t*)alloc((size_t)Hid * Hid);      // wk codes
  int8_t* wb2  = (int8_t*)alloc((size_t)Hid * Hid);      // wv codes
  int8_t* wb3  = (int8_t*)alloc((size_t)Hid * Hid);      // wo codes
  float*  oat  = (float*) alloc((size_t)Bh * Ss * Dh * sizeof(float));
  int8_t* qqb  = (int8_t*)alloc((size_t)Bh * Ss * Dh);
  int8_t* kqb  = (int8_t*)alloc((size_t)Bh * Ss * Dh);
  bf16_t* vdqt = (bf16_t*)alloc((size_t)Bh * Dh * Ss * sizeof(bf16_t));
  float* sxa = (float*)alloc((size_t)Mr * sizeof(float));
  float* sw0 = (float*)alloc((size_t)Hid * sizeof(float));
  float* sw1 = (float*)alloc((size_t)Hid * sizeof(float));
  float* sw2 = (float*)alloc((size_t)Hid * sizeof(float));
  float* sw3 = (float*)alloc((size_t)Hid * sizeof(float));
  float* Fq  = (float*)alloc((size_t)Bh * Ss * sizeof(float));
  float* Fk  = (float*)alloc((size_t)Bh * Ss * sizeof(float));
  float* A2v = (float*)alloc((size_t)Bh * Ss * sizeof(float));
  float* soa = (float*)alloc((size_t)Mr * sizeof(float));
  float* ctab = (float*)alloc((size_t)Ss * 64 * sizeof(float));
  float* stab = (float*)alloc((size_t)Ss * 64 * sizeof(float));
  int8_t* oq  = xq;   // xq dead after QKV GEMM

  rope_table_kernel<<<Ss * 64 / 256, 256, 0, stream>>>(ctab, stab);
  quant_rows_kernel<<<Mr, 256, 0, stream>>>(hidden, xq, sxa, Hid, 127.f, -128.f, 127.f);
  quant_w4_kernel<<<4 * Hid, 256, 0, stream>>>(wq, wk, wv, wo, wb0, wb1, wb2, wb3,
                                               sw0, sw1, sw2, sw3);

  qkv_gemm_kernel<<<768, 256, 0, stream>>>(xq, sxa, wb0, wb1, wb2, sw0, sw1, sw2,
                                           qqb, Fq, kqb, Fk, vdqt, A2v, ctab, stab);

  dim3 ga(Bh, 32);
  attn_kernel<<<ga, 64, 0, stream>>>(qqb, kqb, vdqt, Fq, Fk, A2v, oat);

  quant_rows_kernel<<<Mr, 256, 0, stream>>>(oat, oq, soa, Hid, 127.f, -128.f, 127.f);
  gemm0_kernel<<<512, 256, 0, stream>>>(oq, soa, wb3, sw3, out, Mr, Hid, Hid);
}

// Round 15
// 391.005 us; speedup vs baseline: 1.2968x; 1.2968x over previous
//
#include <hip/hip_runtime.h>
#include <hip/hip_bf16.h>
#include <math.h>
#include <stdint.h>

#define NEG_INF_F (-3.4028234663852886e38f)

typedef __bf16 bf16_t;
typedef __bf16 bf16x8 __attribute__((ext_vector_type(8)));
typedef float f32x4 __attribute__((ext_vector_type(4)));
typedef float f32x16 __attribute__((ext_vector_type(16)));
typedef int i32x4 __attribute__((ext_vector_type(4)));
typedef int i32x16 __attribute__((ext_vector_type(16)));
typedef int8_t c8x4 __attribute__((ext_vector_type(4)));

static constexpr int Bb = 2, Ss = 1024, Hid = 4096, Nh = 32, Dh = 128;
static constexpr int Mr = Bb * Ss;   // 2048 token rows
static constexpr int Bh = Bb * Nh;   // 64 (batch*heads)

__device__ __forceinline__ void gload_lds16(const void* g, void* l) {
  __builtin_amdgcn_global_load_lds((const __attribute__((address_space(1))) void*)g,
                                   (__attribute__((address_space(3))) void*)l, 16, 0, 0);
}

__device__ __forceinline__ float wred_max(float v) {
#pragma unroll
  for (int off = 32; off > 0; off >>= 1) v = fmaxf(v, __shfl_xor(v, off));
  return v;
}

__device__ __forceinline__ unsigned pkbf(float a, float b) {
  unsigned short ua = __builtin_bit_cast(unsigned short, (bf16_t)a);
  unsigned short ub = __builtin_bit_cast(unsigned short, (bf16_t)b);
  return (unsigned)ua | ((unsigned)ub << 16);
}

// ---------------- RoPE cos/sin tables [S][64] ----------------
__global__ void rope_table_kernel(float* __restrict__ ctab, float* __restrict__ stab) {
  int i = blockIdx.x * 256 + threadIdx.x;   // 0 .. S*64-1
  int srow = i >> 6, d = i & 63;
  float invf = (float)pow(10000.0, -((double)(2 * d) / (double)Dh));
  float ang = (float)srow * invf;           // f32 mul like numpy outer()
  ctab[i] = (float)cos((double)ang);
  stab[i] = (float)sin((double)ang);
}

// ------------- per-row symmetric fake-quant: int8 codes + f32 scale -------------
__device__ __forceinline__ void quant_row_body(
    const float* __restrict__ x, int8_t* __restrict__ o, float* __restrict__ scale,
    int row, int ncols, float qmax, float clo, float chi)
{
  const int tid = threadIdx.x;
  const float4* x4 = (const float4*)x;
  const int n4 = ncols >> 2;
  float m = 0.f;
  for (int i = tid; i < n4; i += 256) {
    float4 v = x4[i];
    m = fmaxf(m, fmaxf(fmaxf(fabsf(v.x), fabsf(v.y)), fmaxf(fabsf(v.z), fabsf(v.w))));
  }
  m = wred_max(m);
  __shared__ float red[4];
  if ((tid & 63) == 0) red[tid >> 6] = m;
  __syncthreads();
  m = fmaxf(fmaxf(red[0], red[1]), fmaxf(red[2], red[3]));
  const float s = fmaxf(m / qmax, 1e-8f);
  if (tid == 0) scale[row] = s;
  c8x4* o4 = (c8x4*)o;
  for (int i = tid; i < n4; i += 256) {
    float4 v = x4[i];
    c8x4 r;
    r[0] = (int8_t)(int)fminf(fmaxf(rintf(v.x / s), clo), chi);
    r[1] = (int8_t)(int)fminf(fmaxf(rintf(v.y / s), clo), chi);
    r[2] = (int8_t)(int)fminf(fmaxf(rintf(v.z / s), clo), chi);
    r[3] = (int8_t)(int)fminf(fmaxf(rintf(v.w / s), clo), chi);
    o4[i] = r;
  }
}

__global__ __launch_bounds__(256) void quant_rows_kernel(
    const float* __restrict__ in, int8_t* __restrict__ outq,
    float* __restrict__ scale, int ncols, float qmax, float clo, float chi)
{
  const int row = blockIdx.x;
  quant_row_body(in + (size_t)row * ncols, outq + (size_t)row * ncols, scale,
                 row, ncols, qmax, clo, chi);
}

// 4 weights in one early launch (w4 quant): sel = id>>12, row = id&4095
__global__ __launch_bounds__(256) void quant_w4_kernel(
    const float* __restrict__ w0, const float* __restrict__ w1,
    const float* __restrict__ w2, const float* __restrict__ w3,
    int8_t* __restrict__ o0, int8_t* __restrict__ o1,
    int8_t* __restrict__ o2, int8_t* __restrict__ o3,
    float* __restrict__ s0, float* __restrict__ s1,
    float* __restrict__ s2, float* __restrict__ s3)
{
  const int sel = blockIdx.x >> 12, row = blockIdx.x & 4095;
  const float* in = sel == 0 ? w0 : (sel == 1 ? w1 : (sel == 2 ? w2 : w3));
  int8_t* o = sel == 0 ? o0 : (sel == 1 ? o1 : (sel == 2 ? o2 : o3));
  float* sc = sel == 0 ? s0 : (sel == 1 ? s1 : (sel == 2 ? s2 : s3));
  quant_row_body(in + (size_t)row * Hid, o + (size_t)row * Hid, sc, row, Hid,
                 7.f, -8.f, 7.f);
}

// ================= fused QKV i8 GEMM, BK=128 single-buffer (best-known), fused epilogues =================
// grid 1536; nIdx 0..95: wsel = nIdx>>5 (0:Q 1:K 2:V), head = nIdx&31.
// rows: bm + wm*64 + fm*16 + kg4*4 + j ; cols: bn + fn*32 + wn*16 + l15.
// Bank swizzle (128B rows): slot c of row r holds global chunk c^(r&7);
// source chunk (lane&7)^(lane>>3); read chunk ((g*4+kg4)^(l15&7)) -> 2-way (free).
__global__ __launch_bounds__(256) void qkv_gemm_kernel(
    const int8_t* __restrict__ A, const float* __restrict__ sA,
    const int8_t* __restrict__ wqz, const int8_t* __restrict__ wkz, const int8_t* __restrict__ wvz,
    const float* __restrict__ swq, const float* __restrict__ swk, const float* __restrict__ swv,
    int8_t* __restrict__ qqb, float* __restrict__ Fq,
    int8_t* __restrict__ kqb, float* __restrict__ Fk,
    bf16_t* __restrict__ vdq, float* __restrict__ a2vp,
    const float* __restrict__ ctab, const float* __restrict__ stab)
{
  __shared__ __align__(16) char smem[34816 + 3072];
  int8_t* As = (int8_t*)smem;
  int8_t* Bs = (int8_t*)(smem + 16384);
  float (*s_red)[128][3] = (float (*)[128][3])(smem + 34816);

  const int tid = threadIdx.x, lane = tid & 63, wid = tid >> 6;
  const int id = blockIdx.x;                 // 1536 blocks, 8 XCDs, 12 n-panels each
  const int xcd = id & 7, within = id >> 3;  // within 0..191
  const int nIdx = xcd * 12 + (within >> 4); // 0..95
  const int mIdx = within & 15;
  const int wsel = nIdx >> 5, head = nIdx & 31;
  const int bm = mIdx * 128, bn = head * 128;
  const int8_t* W = wsel == 0 ? wqz : (wsel == 1 ? wkz : wvz);
  const float* sW = wsel == 0 ? swq : (wsel == 1 ? swk : swv);
  constexpr int K = Hid;

  const int wm = wid >> 1, wn = wid & 1;
  const int l15 = lane & 15, kg4 = lane >> 4;

  const int strow = wid * 8 + (lane >> 3);
  const int schunk = ((lane & 7) ^ (lane >> 3)) * 16;
  const int8_t* gA = A + (size_t)(bm + strow) * K + schunk;
  const int8_t* gB = W + (size_t)(bn + strow) * K + schunk;

  i32x4 acc[4][4] = {};
  for (int k0 = 0; k0 < K; k0 += 128) {
    if (k0) __syncthreads();
#pragma unroll
    for (int r = 0; r < 4; ++r) {
      gload_lds16(gA + k0 + (size_t)r * 32 * K, As + r * 4096 + wid * 1024);
      gload_lds16(gB + k0 + (size_t)r * 32 * K, Bs + r * 4096 + wid * 1024);
    }
    __syncthreads();
#pragma unroll
    for (int g = 0; g < 2; ++g) {
      i32x4 af[4], bw[4];
#pragma unroll
      for (int f = 0; f < 4; ++f) {
        const int ca = (((g << 2) | kg4) ^ (l15 & 7)) * 16;
        af[f] = *(const i32x4*)&As[(wm * 64 + f * 16 + l15) * 128 + ca];
        bw[f] = *(const i32x4*)&Bs[(f * 32 + wn * 16 + l15) * 128 + ca];
      }
#pragma unroll
      for (int fm = 0; fm < 4; ++fm)
#pragma unroll
        for (int fn = 0; fn < 4; ++fn)
          acc[fm][fn] = __builtin_amdgcn_mfma_i32_16x16x64_i8(af[fm], bw[fn], acc[fm][fn], 0, 0, 0);
    }
  }

  float sav[4][4], swv_[4];
#pragma unroll
  for (int fm = 0; fm < 4; ++fm)
#pragma unroll
    for (int j = 0; j < 4; ++j) sav[fm][j] = sA[bm + wm * 64 + fm * 16 + kg4 * 4 + j];
#pragma unroll
  for (int fn = 0; fn < 4; ++fn) swv_[fn] = sW[bn + fn * 32 + wn * 16 + l15];

  float val[4][4][4];
#pragma unroll
  for (int fm = 0; fm < 4; ++fm)
#pragma unroll
    for (int fn = 0; fn < 4; ++fn)
#pragma unroll
      for (int j = 0; j < 4; ++j)
        val[fm][fn][j] = (float)acc[fm][fn][j] * sav[fm][j] * swv_[fn];

  const int b = bm >> 10;
  const int bh = b * Nh + head;
  float r_[4][4][4];
  if (wsel != 2) {   // Q or K: rope
    const int dmA = wn * 16 + l15, dmB = 32 + wn * 16 + l15;
#pragma unroll
    for (int fm = 0; fm < 4; ++fm)
#pragma unroll
      for (int j = 0; j < 4; ++j) {
        const int srow = (bm + wm * 64 + fm * 16 + kg4 * 4 + j) & (Ss - 1);
        const float cA = ctab[srow * 64 + dmA], cB = ctab[srow * 64 + dmB];
        const float sA_ = stab[srow * 64 + dmA], sB_ = stab[srow * 64 + dmB];
        r_[fm][0][j] = __fsub_rn(__fmul_rn(val[fm][0][j], cA), __fmul_rn(val[fm][2][j], sA_));
        r_[fm][1][j] = __fsub_rn(__fmul_rn(val[fm][1][j], cB), __fmul_rn(val[fm][3][j], sB_));
        r_[fm][2][j] = __fadd_rn(__fmul_rn(val[fm][2][j], cA), __fmul_rn(val[fm][0][j], sA_));
        r_[fm][3][j] = __fadd_rn(__fmul_rn(val[fm][3][j], cB), __fmul_rn(val[fm][1][j], sB_));
      }
  } else {
#pragma unroll
    for (int fm = 0; fm < 4; ++fm)
#pragma unroll
      for (int fn = 0; fn < 4; ++fn)
#pragma unroll
        for (int j = 0; j < 4; ++j) r_[fm][fn][j] = val[fm][fn][j];
  }
  // per-row (ma, n2): wave-half partial then cross-wn via s_red
  float ma_[4][4], n2_[4][4];
#pragma unroll
  for (int fm = 0; fm < 4; ++fm)
#pragma unroll
    for (int j = 0; j < 4; ++j) {
      float ma = 0.f, n2 = 0.f;
#pragma unroll
      for (int fn = 0; fn < 4; ++fn) {
        const float x = r_[fm][fn][j];
        ma = fmaxf(ma, fabsf(x));
        n2 += x * x;
      }
#pragma unroll
      for (int off = 1; off < 16; off <<= 1) {
        ma = fmaxf(ma, __shfl_xor(ma, off));
        n2 += __shfl_xor(n2, off);
      }
      ma_[fm][j] = ma;
      n2_[fm][j] = n2;
    }
  if (l15 == 0) {
#pragma unroll
    for (int fm = 0; fm < 4; ++fm)
#pragma unroll
      for (int j = 0; j < 4; ++j) {
        const int rl = wm * 64 + fm * 16 + kg4 * 4 + j;
        s_red[wn][rl][0] = ma_[fm][j];
        s_red[wn][rl][1] = n2_[fm][j];
      }
  }
  __syncthreads();   // also retires As/Bs for the vt reuse below
  float qc[4][4][4], svl[4][4], n2c[4][4], nq2_[4][4];
#pragma unroll
  for (int fm = 0; fm < 4; ++fm)
#pragma unroll
    for (int j = 0; j < 4; ++j) {
      const int rl = wm * 64 + fm * 16 + kg4 * 4 + j;
      const float ma = fmaxf(ma_[fm][j], s_red[wn ^ 1][rl][0]);
      const float n2 = n2_[fm][j] + s_red[wn ^ 1][rl][1];
      const float s = fmaxf(ma / 127.0f, 1e-8f);
      float nq2 = 0.f;
#pragma unroll
      for (int fn = 0; fn < 4; ++fn) {
        const float q = fminf(fmaxf(rintf(r_[fm][fn][j] / s), -128.f), 127.f);
        qc[fm][fn][j] = q;
        nq2 += q * q;
      }
#pragma unroll
      for (int off = 1; off < 16; off <<= 1) nq2 += __shfl_xor(nq2, off);
      svl[fm][j] = s;
      n2c[fm][j] = n2;
      nq2_[fm][j] = nq2;
    }
  __syncthreads();
  if (l15 == 0) {
#pragma unroll
    for (int fm = 0; fm < 4; ++fm)
#pragma unroll
      for (int j = 0; j < 4; ++j)
        s_red[wn][wm * 64 + fm * 16 + kg4 * 4 + j][2] = nq2_[fm][j];
  }
  __syncthreads();

  if (wsel != 2) {
    int8_t* outq = (wsel == 0) ? qqb : kqb;
    float* Ff = (wsel == 0) ? Fq : Fk;
#pragma unroll
    for (int fm = 0; fm < 4; ++fm)
#pragma unroll
      for (int j = 0; j < 4; ++j) {
        const int rl = wm * 64 + fm * 16 + kg4 * 4 + j;
        const int stok = (bm + rl) & (Ss - 1);
        const size_t rowBase = ((size_t)bh * Ss + stok) * Dh;
#pragma unroll
        for (int fn = 0; fn < 4; ++fn)
          outq[rowBase + fn * 32 + wn * 16 + l15] = (int8_t)(int)qc[fm][fn][j];
        if (wn == 0 && l15 == 0) {
          const float nq2 = nq2_[fm][j] + s_red[1][rl][2];
          Ff[(size_t)bh * Ss + stok] = sqrtf(n2c[fm][j] / nq2) * 0.2973017787506803f;
        }
      }
  } else {
    bf16_t* svt = (bf16_t*)smem;   // reuses As/Bs region (retired above)
#pragma unroll
    for (int fm = 0; fm < 4; ++fm)
#pragma unroll
      for (int j = 0; j < 4; ++j) {
        const int t = wm * 64 + fm * 16 + kg4 * 4 + j;
#pragma unroll
        for (int fn = 0; fn < 4; ++fn) {
          const int d = fn * 32 + wn * 16 + l15;
          svt[d * 136 + t] = (bf16_t)(qc[fm][fn][j] * svl[fm][j]);
        }
        if (wn == 0 && l15 == 0) {
          const float nq2 = nq2_[fm][j] + s_red[1][t][2];
          a2vp[(size_t)bh * Ss + ((bm + t) & (Ss - 1))] =
              svl[fm][j] * sqrtf(nq2) / sqrtf(n2c[fm][j]);
        }
      }
    __syncthreads();
    const int d = tid >> 1, toff = (tid & 1) * 64;
    const int s0 = bm & (Ss - 1);
    const bf16_t* src = svt + d * 136 + toff;
    bf16_t* dst = vdq + ((size_t)bh * Dh + d) * Ss + s0 + toff;
#pragma unroll
    for (int k = 0; k < 8; ++k) {
      bf16x8 tv;
#pragma unroll
      for (int e = 0; e < 8; ++e) tv[e] = src[k * 8 + e];
      *(bf16x8*)(dst + k * 8) = tv;
    }
  }
}

// ===== output i8 GEMM: BK=128 single-buffer 2-barrier core (best at 512 blocks) =====
__global__ __launch_bounds__(256) void gemm0_kernel(
    const int8_t* __restrict__ A, const float* __restrict__ sA,
    const int8_t* __restrict__ W, const float* __restrict__ sW,
    float* __restrict__ out, int M, int N, int K)
{
  __shared__ __align__(16) int8_t As[128 * 128];
  __shared__ __align__(16) int8_t Bs[128 * 128];
  const int tid = threadIdx.x, lane = tid & 63, wid = tid >> 6;
  const int id = blockIdx.x;
  const int xcd = id & 7, within = id >> 3;
  const int nIdx = xcd * 4 + (within >> 4);
  const int mIdx = within & 15;
  const int bm = mIdx * 128, bn = nIdx * 128;
  const int wm = wid >> 1, wn = wid & 1;
  const int l15 = lane & 15, kg4 = lane >> 4;

  const int strow = wid * 8 + (lane >> 3);
  const int schunk = ((lane & 7) ^ (lane >> 3)) * 16;
  const int8_t* gA = A + (size_t)(bm + strow) * K + schunk;
  const int8_t* gB = W + (size_t)(bn + strow) * K + schunk;

  i32x4 acc[4][4] = {};
  for (int k0 = 0; k0 < K; k0 += 128) {
    if (k0) __syncthreads();
#pragma unroll
    for (int r = 0; r < 4; ++r) {
      gload_lds16(gA + k0 + (size_t)r * 32 * K, As + r * 4096 + wid * 1024);
      gload_lds16(gB + k0 + (size_t)r * 32 * K, Bs + r * 4096 + wid * 1024);
    }
    __syncthreads();
#pragma unroll
    for (int g = 0; g < 2; ++g) {
      i32x4 af[4], bw[4];
#pragma unroll
      for (int f = 0; f < 4; ++f) {
        const int ca = (((g << 2) | kg4) ^ (l15 & 7)) * 16;
        af[f] = *(const i32x4*)&As[(wm * 64 + f * 16 + l15) * 128 + ca];
        bw[f] = *(const i32x4*)&Bs[(f * 32 + wn * 16 + l15) * 128 + ca];
      }
#pragma unroll
      for (int fm = 0; fm < 4; ++fm)
#pragma unroll
        for (int fn = 0; fn < 4; ++fn)
          acc[fm][fn] = __builtin_amdgcn_mfma_i32_16x16x64_i8(af[fm], bw[fn], acc[fm][fn], 0, 0, 0);
    }
  }
#pragma unroll
  for (int fm = 0; fm < 4; ++fm) {
#pragma unroll
    for (int j = 0; j < 4; ++j) {
      const int row = bm + wm * 64 + fm * 16 + kg4 * 4 + j;
      const float sa = sA[row];
#pragma unroll
      for (int fn = 0; fn < 4; ++fn) {
        const int col = bn + fn * 32 + wn * 16 + l15;
        out[(size_t)row * N + col] = (float)acc[fm][fn][j] * sa * sW[col];
      }
    }
  }
}

// ------------- fused attention: 1 wave per 32 q-rows, no LDS, no barriers -------------
// grid (Bh, 32); unit u = 31 - blockIdx.y (heavy-first); q0 = u*32; nt = u+1 k-tiles.
#define KR(r) (((r) & 3) + 8 * ((r) >> 2) + 4 * hi)
__global__ __launch_bounds__(64, 2) void attn_kernel(
    const int8_t* __restrict__ qq, const int8_t* __restrict__ kq,
    const bf16_t* __restrict__ vdqt,
    const float* __restrict__ Fq, const float* __restrict__ Fk,
    const float* __restrict__ A2v, float* __restrict__ oattn)
{
  const int bh = blockIdx.x, b = bh >> 5, h = bh & 31;
  const int lane = threadIdx.x & 63;
  const int l31 = lane & 31, hi = lane >> 5;
  const int u = 31 - (int)blockIdx.y;
  const int q0 = u * 32;
  const int nt = u + 1;
  const size_t bhS = (size_t)bh * Ss;

  const int8_t* qrow = qq + (bhS + q0 + l31) * Dh + hi * 16;
  i32x4 qf[4];
#pragma unroll
  for (int c = 0; c < 4; ++c) qf[c] = *(const i32x4*)(qrow + c * 32);
  const float fq = Fq[bhS + q0 + l31];
  const int qcol = q0 + l31;

  float m = NEG_INF_F;
  int t = 0;
  for (; t + 1 < nt; t += 2) {
    const int kb0 = t * 32, kb1 = kb0 + 32;
    const int8_t* kr0 = kq + (bhS + kb0 + l31) * Dh + hi * 16;
    const int8_t* kr1 = kq + (bhS + kb1 + l31) * Dh + hi * 16;
    i32x16 ca = {}, cb = {}, da = {}, db = {};
    ca = __builtin_amdgcn_mfma_i32_32x32x32_i8(*(const i32x4*)(kr0),      qf[0], ca, 0, 0, 0);
    cb = __builtin_amdgcn_mfma_i32_32x32x32_i8(*(const i32x4*)(kr0 + 64), qf[2], cb, 0, 0, 0);
    da = __builtin_amdgcn_mfma_i32_32x32x32_i8(*(const i32x4*)(kr1),      qf[0], da, 0, 0, 0);
    db = __builtin_amdgcn_mfma_i32_32x32x32_i8(*(const i32x4*)(kr1 + 64), qf[2], db, 0, 0, 0);
    ca = __builtin_amdgcn_mfma_i32_32x32x32_i8(*(const i32x4*)(kr0 + 32), qf[1], ca, 0, 0, 0);
    cb = __builtin_amdgcn_mfma_i32_32x32x32_i8(*(const i32x4*)(kr0 + 96), qf[3], cb, 0, 0, 0);
    da = __builtin_amdgcn_mfma_i32_32x32x32_i8(*(const i32x4*)(kr1 + 32), qf[1], da, 0, 0, 0);
    db = __builtin_amdgcn_mfma_i32_32x32x32_i8(*(const i32x4*)(kr1 + 96), qf[3], db, 0, 0, 0);
    float4 fk40[4], fk41[4];
#pragma unroll
    for (int g = 0; g < 4; ++g) fk40[g] = *(const float4*)&Fk[bhS + kb0 + g * 8 + 4 * hi];
#pragma unroll
    for (int g = 0; g < 4; ++g) fk41[g] = *(const float4*)&Fk[bhS + kb1 + g * 8 + 4 * hi];
    const bool diag1 = (t + 1 == nt - 1);
#pragma unroll
    for (int r = 0; r < 16; ++r) {
      m = fmaxf(m, (float)(ca[r] + cb[r]) * fq * ((const float*)&fk40[r >> 2])[r & 3]);
      const float v1 = (float)(da[r] + db[r]) * fq * ((const float*)&fk41[r >> 2])[r & 3];
      if (!diag1 || (kb1 + KR(r) <= qcol)) m = fmaxf(m, v1);
    }
  }
  if (t < nt) {
    const int kb = t * 32;
    const int8_t* krow = kq + (bhS + kb + l31) * Dh + hi * 16;
    i32x16 ca = {}, cb = {};
    ca = __builtin_amdgcn_mfma_i32_32x32x32_i8(*(const i32x4*)(krow),      qf[0], ca, 0, 0, 0);
    cb = __builtin_amdgcn_mfma_i32_32x32x32_i8(*(const i32x4*)(krow + 64), qf[2], cb, 0, 0, 0);
    ca = __builtin_amdgcn_mfma_i32_32x32x32_i8(*(const i32x4*)(krow + 32), qf[1], ca, 0, 0, 0);
    cb = __builtin_amdgcn_mfma_i32_32x32x32_i8(*(const i32x4*)(krow + 96), qf[3], cb, 0, 0, 0);
    float4 fk4[4];
#pragma unroll
    for (int g = 0; g < 4; ++g) fk4[g] = *(const float4*)&Fk[bhS + kb + g * 8 + 4 * hi];
#pragma unroll
    for (int r = 0; r < 16; ++r) {
      const float v = (float)(ca[r] + cb[r]) * fq * ((const float*)&fk4[r >> 2])[r & 3];
      if (kb + KR(r) <= qcol) m = fmaxf(m, v);
    }
  }
  m = fmaxf(m, __shfl_xor(m, 32));

  float z = 0.f;
  f32x16 oacc[4] = {};
  for (int tt = 0; tt < nt; ++tt) {
    const int kb = tt * 32;
    const int8_t* krow = kq + (bhS + kb + l31) * Dh + hi * 16;
    i32x16 ca = {}, cb = {};
    ca = __builtin_amdgcn_mfma_i32_32x32x32_i8(*(const i32x4*)(krow),      qf[0], ca, 0, 0, 0);
    cb = __builtin_amdgcn_mfma_i32_32x32x32_i8(*(const i32x4*)(krow + 64), qf[2], cb, 0, 0, 0);
    ca = __builtin_amdgcn_mfma_i32_32x32x32_i8(*(const i32x4*)(krow + 32), qf[1], ca, 0, 0, 0);
    cb = __builtin_amdgcn_mfma_i32_32x32x32_i8(*(const i32x4*)(krow + 96), qf[3], cb, 0, 0, 0);
    float4 fk4[4];
#pragma unroll
    for (int g = 0; g < 4; ++g) fk4[g] = *(const float4*)&Fk[bhS + kb + g * 8 + 4 * hi];
    float p[16];
    const bool diag = (tt == nt - 1);
#pragma unroll
    for (int r = 0; r < 16; ++r) {
      float v = (float)(ca[r] + cb[r]) * fq * ((const float*)&fk4[r >> 2])[r & 3];
      if (diag && (kb + KR(r) > qcol)) v = NEG_INF_F;
      const float e = __expf(v - m);
      z += e;
      p[r] = rintf(127.0f * e);
    }
#pragma unroll
    for (int s = 0; s < 2; ++s) {
      const int rs = s * 8;
      unsigned k0 = pkbf(p[rs + 0], p[rs + 1]);
      unsigned k1 = pkbf(p[rs + 2], p[rs + 3]);
      unsigned k2 = pkbf(p[rs + 4], p[rs + 5]);
      unsigned k3 = pkbf(p[rs + 6], p[rs + 7]);
      unsigned sx0 = __shfl_xor(k0, 32);
      unsigned sx1 = __shfl_xor(k1, 32);
      unsigned sx2 = __shfl_xor(k2, 32);
      unsigned sx3 = __shfl_xor(k3, 32);
      uint4 ww;
      ww.x = hi ? sx2 : k0;
      ww.y = hi ? sx3 : k1;
      ww.z = hi ? k2 : sx0;
      ww.w = hi ? k3 : sx1;
      const bf16x8 af = __builtin_bit_cast(bf16x8, ww);
      const int kg2 = kb + s * 16 + hi * 8;
#pragma unroll
      for (int dt = 0; dt < 4; ++dt) {
        const bf16x8 vf = *(const bf16x8*)(vdqt + ((size_t)bh * Dh + dt * 32 + l31) * Ss + kg2);
        oacc[dt] = __builtin_amdgcn_mfma_f32_32x32x16_bf16(af, vf, oacc[dt], 0, 0, 0);
      }
    }
  }
  z += __shfl_xor(z, 32);
  const float osc = (1.0f / z) / 127.0f / A2v[bhS + q0 + l31];
#pragma unroll
  for (int dt = 0; dt < 4; ++dt) {
#pragma unroll
    for (int r = 0; r < 16; ++r) {
      const int q = q0 + KR(r);
      const float oscr = __shfl(osc, KR(r));
      oattn[((size_t)b * Ss + q) * Hid + h * Dh + dt * 32 + l31] = oacc[dt][r] * oscr;
    }
  }
}

extern "C" void kernel_launch(void* const* d_in, const int* in_sizes, int n_in,
                              void* d_out, int out_size, void* d_ws, size_t ws_size,
                              hipStream_t stream)
{
  const float* hidden = (const float*)d_in[0];
  const float* wq = (const float*)d_in[1];
  const float* wk = (const float*)d_in[2];
  const float* wv = (const float*)d_in[3];
  const float* wo = (const float*)d_in[4];
  float* out = (float*)d_out;

  char* p = (char*)d_ws;
  auto alloc = [&](size_t bytes) -> char* {
    char* r = p; p += (bytes + 255) & ~(size_t)255; return r;
  };
  int8_t* xq   = (int8_t*)alloc((size_t)Mr * Hid);       // later reused for oq
  int8_t* wb0  = (int8_t*)alloc((size_t)Hid * Hid);      // wq codes
  int8_t* wb1  = (int8_t*)alloc((size_t)Hid * Hid);      // wk codes
  int8_t* wb2  = (int8_t*)alloc((size_t)Hid * Hid);      // wv codes
  int8_t* wb3  = (int8_t*)alloc((size_t)Hid * Hid);      // wo codes
  float*  oat  = (float*) alloc((size_t)Bh * Ss * Dh * sizeof(float));
  int8_t* qqb  = (int8_t*)alloc((size_t)Bh * Ss * Dh);
  int8_t* kqb  = (int8_t*)alloc((size_t)Bh * Ss * Dh);
  bf16_t* vdqt = (bf16_t*)alloc((size_t)Bh * Dh * Ss * sizeof(bf16_t));
  float* sxa = (float*)alloc((size_t)Mr * sizeof(float));
  float* sw0 = (float*)alloc((size_t)Hid * sizeof(float));
  float* sw1 = (float*)alloc((size_t)Hid * sizeof(float));
  float* sw2 = (float*)alloc((size_t)Hid * sizeof(float));
  float* sw3 = (float*)alloc((size_t)Hid * sizeof(float));
  float* Fq  = (float*)alloc((size_t)Bh * Ss * sizeof(float));
  float* Fk  = (float*)alloc((size_t)Bh * Ss * sizeof(float));
  float* A2v = (float*)alloc((size_t)Bh * Ss * sizeof(float));
  float* soa = (float*)alloc((size_t)Mr * sizeof(float));
  float* ctab = (float*)alloc((size_t)Ss * 64 * sizeof(float));
  float* stab = (float*)alloc((size_t)Ss * 64 * sizeof(float));
  int8_t* oq  = xq;   // xq dead after QKV GEMM

  rope_table_kernel<<<Ss * 64 / 256, 256, 0, stream>>>(ctab, stab);
  quant_rows_kernel<<<Mr, 256, 0, stream>>>(hidden, xq, sxa, Hid, 127.f, -128.f, 127.f);
  quant_w4_kernel<<<4 * Hid, 256, 0, stream>>>(wq, wk, wv, wo, wb0, wb1, wb2, wb3,
                                               sw0, sw1, sw2, sw3);

  qkv_gemm_kernel<<<1536, 256, 0, stream>>>(xq, sxa, wb0, wb1, wb2, sw0, sw1, sw2,
                                            qqb, Fq, kqb, Fk, vdqt, A2v, ctab, stab);

  dim3 ga(Bh, 32);
  attn_kernel<<<ga, 64, 0, stream>>>(qqb, kqb, vdqt, Fq, Fk, A2v, oat);

  quant_rows_kernel<<<Mr, 256, 0, stream>>>(oat, oq, soa, Hid, 127.f, -128.f, 127.f);
  gemm0_kernel<<<512, 256, 0, stream>>>(oq, soa, wb3, sw3, out, Mr, Hid, Hid);
}

// Round 16
// 375.959 us; speedup vs baseline: 1.3487x; 1.0400x over previous
//
#include <hip/hip_runtime.h>
#include <hip/hip_bf16.h>
#include <math.h>
#include <stdint.h>

#define NEG_INF_F (-3.4028234663852886e38f)

typedef __bf16 bf16_t;
typedef __bf16 bf16x8 __attribute__((ext_vector_type(8)));
typedef float f32x4 __attribute__((ext_vector_type(4)));
typedef float f32x16 __attribute__((ext_vector_type(16)));
typedef int i32x4 __attribute__((ext_vector_type(4)));
typedef int i32x16 __attribute__((ext_vector_type(16)));
typedef int8_t c8x4 __attribute__((ext_vector_type(4)));

static constexpr int Bb = 2, Ss = 1024, Hid = 4096, Nh = 32, Dh = 128;
static constexpr int Mr = Bb * Ss;   // 2048 token rows
static constexpr int Bh = Bb * Nh;   // 64 (batch*heads)

__device__ __forceinline__ void gload_lds16(const void* g, void* l) {
  __builtin_amdgcn_global_load_lds((const __attribute__((address_space(1))) void*)g,
                                   (__attribute__((address_space(3))) void*)l, 16, 0, 0);
}

__device__ __forceinline__ float wred_max(float v) {
#pragma unroll
  for (int off = 32; off > 0; off >>= 1) v = fmaxf(v, __shfl_xor(v, off));
  return v;
}

__device__ __forceinline__ unsigned pkbf(float a, float b) {
  unsigned short ua = __builtin_bit_cast(unsigned short, (bf16_t)a);
  unsigned short ub = __builtin_bit_cast(unsigned short, (bf16_t)b);
  return (unsigned)ua | ((unsigned)ub << 16);
}

// ---------------- RoPE cos/sin tables [S][64] ----------------
__global__ void rope_table_kernel(float* __restrict__ ctab, float* __restrict__ stab) {
  int i = blockIdx.x * 256 + threadIdx.x;   // 0 .. S*64-1
  int srow = i >> 6, d = i & 63;
  float invf = (float)pow(10000.0, -((double)(2 * d) / (double)Dh));
  float ang = (float)srow * invf;           // f32 mul like numpy outer()
  ctab[i] = (float)cos((double)ang);
  stab[i] = (float)sin((double)ang);
}

// ------------- per-row symmetric fake-quant: int8 codes + f32 scale -------------
__device__ __forceinline__ void quant_row_body(
    const float* __restrict__ x, int8_t* __restrict__ o, float* __restrict__ scale,
    int row, int ncols, float qmax, float clo, float chi)
{
  const int tid = threadIdx.x;
  const float4* x4 = (const float4*)x;
  const int n4 = ncols >> 2;
  float m = 0.f;
  for (int i = tid; i < n4; i += 256) {
    float4 v = x4[i];
    m = fmaxf(m, fmaxf(fmaxf(fabsf(v.x), fabsf(v.y)), fmaxf(fabsf(v.z), fabsf(v.w))));
  }
  m = wred_max(m);
  __shared__ float red[4];
  if ((tid & 63) == 0) red[tid >> 6] = m;
  __syncthreads();
  m = fmaxf(fmaxf(red[0], red[1]), fmaxf(red[2], red[3]));
  const float s = fmaxf(m / qmax, 1e-8f);
  if (tid == 0) scale[row] = s;
  c8x4* o4 = (c8x4*)o;
  for (int i = tid; i < n4; i += 256) {
    float4 v = x4[i];
    c8x4 r;
    r[0] = (int8_t)(int)fminf(fmaxf(rintf(v.x / s), clo), chi);
    r[1] = (int8_t)(int)fminf(fmaxf(rintf(v.y / s), clo), chi);
    r[2] = (int8_t)(int)fminf(fmaxf(rintf(v.z / s), clo), chi);
    r[3] = (int8_t)(int)fminf(fmaxf(rintf(v.w / s), clo), chi);
    o4[i] = r;
  }
}

__global__ __launch_bounds__(256) void quant_rows_kernel(
    const float* __restrict__ in, int8_t* __restrict__ outq,
    float* __restrict__ scale, int ncols, float qmax, float clo, float chi)
{
  const int row = blockIdx.x;
  quant_row_body(in + (size_t)row * ncols, outq + (size_t)row * ncols, scale,
                 row, ncols, qmax, clo, chi);
}

// 3 weights in one launch (w4 quant): sel = id>>12, row = id&4095
__global__ __launch_bounds__(256) void quant_w3_kernel(
    const float* __restrict__ w0, const float* __restrict__ w1, const float* __restrict__ w2,
    int8_t* __restrict__ o0, int8_t* __restrict__ o1, int8_t* __restrict__ o2,
    float* __restrict__ s0, float* __restrict__ s1, float* __restrict__ s2)
{
  const int sel = blockIdx.x >> 12, row = blockIdx.x & 4095;
  const float* in = sel == 0 ? w0 : (sel == 1 ? w1 : w2);
  int8_t* o = sel == 0 ? o0 : (sel == 1 ? o1 : o2);
  float* sc = sel == 0 ? s0 : (sel == 1 ? s1 : s2);
  quant_row_body(in + (size_t)row * Hid, o + (size_t)row * Hid, sc, row, Hid,
                 7.f, -8.f, 7.f);
}

// ===== K-loop: BK=128 double-buffered pipeline with COUNTED vmcnt + raw barriers =====
// Best-measured qkv core (186.5 µs, R12/R13): never drains vmcnt to 0 in main loop;
// 2 tiles = 16 loads/wave in flight, vmcnt(8) waits only the current tile.
#define GEMM_WAITBAR(N)                                                               \
  asm volatile("s_waitcnt vmcnt(" #N ")" ::: "memory");                               \
  __builtin_amdgcn_sched_barrier(0);                                                  \
  __builtin_amdgcn_s_barrier();                                                       \
  __builtin_amdgcn_sched_barrier(0);

#define GEMM_BARONLY                                                                  \
  __builtin_amdgcn_sched_barrier(0);                                                  \
  __builtin_amdgcn_s_barrier();                                                       \
  __builtin_amdgcn_sched_barrier(0);

#define GEMM_STAGE128(koff, Abuf, Bbuf)                                               \
  _Pragma("unroll")                                                                   \
  for (int r = 0; r < 4; ++r) {                                                       \
    gload_lds16(gA + (koff) + (size_t)r * 32 * K, (Abuf) + r * 4096 + wid * 1024);    \
    gload_lds16(gB + (koff) + (size_t)r * 32 * K, (Bbuf) + r * 4096 + wid * 1024);    \
  }

#define GEMM_PHASE128(Abuf, Bbuf)                                                     \
  _Pragma("unroll")                                                                   \
  for (int g = 0; g < 2; ++g) {                                                       \
    i32x4 af[4], bw[4];                                                               \
    _Pragma("unroll")                                                                 \
    for (int f = 0; f < 4; ++f) {                                                     \
      const int ca = (((g << 2) | kg4) ^ (l15 & 7)) * 16;                             \
      af[f] = *(const i32x4*)&(Abuf)[(wm * 64 + f * 16 + l15) * 128 + ca];            \
      bw[f] = *(const i32x4*)&(Bbuf)[(f * 32 + wn * 16 + l15) * 128 + ca];            \
    }                                                                                 \
    _Pragma("unroll")                                                                 \
    for (int fm = 0; fm < 4; ++fm)                                                    \
      _Pragma("unroll")                                                               \
      for (int fn = 0; fn < 4; ++fn)                                                  \
        acc[fm][fn] = __builtin_amdgcn_mfma_i32_16x16x64_i8(af[fm], bw[fn],           \
                                                            acc[fm][fn], 0, 0, 0);   \
  }

#define GEMM_CORE_PIPE(SMEM)                                                          \
  int8_t* A0 = (int8_t*)(SMEM);                                                       \
  int8_t* A1 = (int8_t*)(SMEM) + 16384;                                               \
  int8_t* B0 = (int8_t*)(SMEM) + 32768;                                               \
  int8_t* B1 = (int8_t*)(SMEM) + 49152;                                               \
  const int strow = wid * 8 + (lane >> 3);                                            \
  const int schunk = ((lane & 7) ^ (lane >> 3)) * 16;                                 \
  const int8_t* gA = A + (size_t)(bm + strow) * K + schunk;                           \
  const int8_t* gB = W + (size_t)(bn + strow) * K + schunk;                           \
  i32x4 acc[4][4] = {};                                                               \
  GEMM_STAGE128(0, A0, B0)                                                            \
  GEMM_STAGE128(128, A1, B1)                                                          \
  for (int k0 = 0; k0 + 512 <= K; k0 += 256) {                                        \
    GEMM_WAITBAR(8)                                                                   \
    GEMM_PHASE128(A0, B0)                                                             \
    GEMM_BARONLY                                                                      \
    GEMM_STAGE128(k0 + 256, A0, B0)                                                   \
    GEMM_WAITBAR(8)                                                                   \
    GEMM_PHASE128(A1, B1)                                                             \
    GEMM_BARONLY                                                                      \
    GEMM_STAGE128(k0 + 384, A1, B1)                                                   \
  }                                                                                   \
  GEMM_WAITBAR(8)                                                                     \
  GEMM_PHASE128(A0, B0)                                                               \
  GEMM_BARONLY                                                                        \
  GEMM_WAITBAR(0)                                                                     \
  GEMM_PHASE128(A1, B1)

// ================= fused QKV i8 GEMM, counted-vmcnt pipeline, fused epilogues =================
__global__ __launch_bounds__(256) void qkv_gemm_kernel(
    const int8_t* __restrict__ A, const float* __restrict__ sA,
    const int8_t* __restrict__ wqz, const int8_t* __restrict__ wkz, const int8_t* __restrict__ wvz,
    const float* __restrict__ swq, const float* __restrict__ swk, const float* __restrict__ swv,
    int8_t* __restrict__ qqb, float* __restrict__ Fq,
    int8_t* __restrict__ kqb, float* __restrict__ Fk,
    bf16_t* __restrict__ vdq, float* __restrict__ a2vp,
    const float* __restrict__ ctab, const float* __restrict__ stab)
{
  __shared__ __align__(16) char smem[65536 + 3072];
  float (*s_red)[128][3] = (float (*)[128][3])(smem + 65536);

  const int tid = threadIdx.x, lane = tid & 63, wid = tid >> 6;
  const int id = blockIdx.x;                 // 1536 blocks, 8 XCDs, 12 n-panels each
  const int xcd = id & 7, within = id >> 3;  // within 0..191
  const int nIdx = xcd * 12 + (within >> 4); // 0..95
  const int mIdx = within & 15;
  const int wsel = nIdx >> 5, head = nIdx & 31;
  const int bm = mIdx * 128, bn = head * 128;
  const int8_t* W = wsel == 0 ? wqz : (wsel == 1 ? wkz : wvz);
  const float* sW = wsel == 0 ? swq : (wsel == 1 ? swk : swv);
  constexpr int K = Hid;

  const int wm = wid >> 1, wn = wid & 1;
  const int l15 = lane & 15, kg4 = lane >> 4;

  GEMM_CORE_PIPE(smem)

  float sav[4][4], swv_[4];
#pragma unroll
  for (int fm = 0; fm < 4; ++fm)
#pragma unroll
    for (int j = 0; j < 4; ++j) sav[fm][j] = sA[bm + wm * 64 + fm * 16 + kg4 * 4 + j];
#pragma unroll
  for (int fn = 0; fn < 4; ++fn) swv_[fn] = sW[bn + fn * 32 + wn * 16 + l15];

  float val[4][4][4];
#pragma unroll
  for (int fm = 0; fm < 4; ++fm)
#pragma unroll
    for (int fn = 0; fn < 4; ++fn)
#pragma unroll
      for (int j = 0; j < 4; ++j)
        val[fm][fn][j] = (float)acc[fm][fn][j] * sav[fm][j] * swv_[fn];

  const int b = bm >> 10;
  const int bh = b * Nh + head;
  float r_[4][4][4];
  if (wsel != 2) {   // Q or K: rope
    const int dmA = wn * 16 + l15, dmB = 32 + wn * 16 + l15;
#pragma unroll
    for (int fm = 0; fm < 4; ++fm)
#pragma unroll
      for (int j = 0; j < 4; ++j) {
        const int srow = (bm + wm * 64 + fm * 16 + kg4 * 4 + j) & (Ss - 1);
        const float cA = ctab[srow * 64 + dmA], cB = ctab[srow * 64 + dmB];
        const float sA_ = stab[srow * 64 + dmA], sB_ = stab[srow * 64 + dmB];
        r_[fm][0][j] = __fsub_rn(__fmul_rn(val[fm][0][j], cA), __fmul_rn(val[fm][2][j], sA_));
        r_[fm][1][j] = __fsub_rn(__fmul_rn(val[fm][1][j], cB), __fmul_rn(val[fm][3][j], sB_));
        r_[fm][2][j] = __fadd_rn(__fmul_rn(val[fm][2][j], cA), __fmul_rn(val[fm][0][j], sA_));
        r_[fm][3][j] = __fadd_rn(__fmul_rn(val[fm][3][j], cB), __fmul_rn(val[fm][1][j], sB_));
      }
  } else {
#pragma unroll
    for (int fm = 0; fm < 4; ++fm)
#pragma unroll
      for (int fn = 0; fn < 4; ++fn)
#pragma unroll
        for (int j = 0; j < 4; ++j) r_[fm][fn][j] = val[fm][fn][j];
  }
  // per-row (ma, n2): wave-half partial then cross-wn via s_red
  float ma_[4][4], n2_[4][4];
#pragma unroll
  for (int fm = 0; fm < 4; ++fm)
#pragma unroll
    for (int j = 0; j < 4; ++j) {
      float ma = 0.f, n2 = 0.f;
#pragma unroll
      for (int fn = 0; fn < 4; ++fn) {
        const float x = r_[fm][fn][j];
        ma = fmaxf(ma, fabsf(x));
        n2 += x * x;
      }
#pragma unroll
      for (int off = 1; off < 16; off <<= 1) {
        ma = fmaxf(ma, __shfl_xor(ma, off));
        n2 += __shfl_xor(n2, off);
      }
      ma_[fm][j] = ma;
      n2_[fm][j] = n2;
    }
  if (l15 == 0) {
#pragma unroll
    for (int fm = 0; fm < 4; ++fm)
#pragma unroll
      for (int j = 0; j < 4; ++j) {
        const int rl = wm * 64 + fm * 16 + kg4 * 4 + j;
        s_red[wn][rl][0] = ma_[fm][j];
        s_red[wn][rl][1] = n2_[fm][j];
      }
  }
  __syncthreads();
  float qc[4][4][4], svl[4][4], n2c[4][4], nq2_[4][4];
#pragma unroll
  for (int fm = 0; fm < 4; ++fm)
#pragma unroll
    for (int j = 0; j < 4; ++j) {
      const int rl = wm * 64 + fm * 16 + kg4 * 4 + j;
      const float ma = fmaxf(ma_[fm][j], s_red[wn ^ 1][rl][0]);
      const float n2 = n2_[fm][j] + s_red[wn ^ 1][rl][1];
      const float s = fmaxf(ma / 127.0f, 1e-8f);
      float nq2 = 0.f;
#pragma unroll
      for (int fn = 0; fn < 4; ++fn) {
        const float q = fminf(fmaxf(rintf(r_[fm][fn][j] / s), -128.f), 127.f);
        qc[fm][fn][j] = q;
        nq2 += q * q;
      }
#pragma unroll
      for (int off = 1; off < 16; off <<= 1) nq2 += __shfl_xor(nq2, off);
      svl[fm][j] = s;
      n2c[fm][j] = n2;
      nq2_[fm][j] = nq2;
    }
  __syncthreads();
  if (l15 == 0) {
#pragma unroll
    for (int fm = 0; fm < 4; ++fm)
#pragma unroll
      for (int j = 0; j < 4; ++j)
        s_red[wn][wm * 64 + fm * 16 + kg4 * 4 + j][2] = nq2_[fm][j];
  }
  __syncthreads();

  if (wsel != 2) {
    int8_t* outq = (wsel == 0) ? qqb : kqb;
    float* Ff = (wsel == 0) ? Fq : Fk;
#pragma unroll
    for (int fm = 0; fm < 4; ++fm)
#pragma unroll
      for (int j = 0; j < 4; ++j) {
        const int rl = wm * 64 + fm * 16 + kg4 * 4 + j;
        const int stok = (bm + rl) & (Ss - 1);
        const size_t rowBase = ((size_t)bh * Ss + stok) * Dh;
#pragma unroll
        for (int fn = 0; fn < 4; ++fn)
          outq[rowBase + fn * 32 + wn * 16 + l15] = (int8_t)(int)qc[fm][fn][j];
        if (wn == 0 && l15 == 0) {
          const float nq2 = nq2_[fm][j] + s_red[1][rl][2];
          Ff[(size_t)bh * Ss + stok] = sqrtf(n2c[fm][j] / nq2) * 0.2973017787506803f;
        }
      }
  } else {
    bf16_t* svt = (bf16_t*)smem;   // reuses pipeline buffers (retired above)
#pragma unroll
    for (int fm = 0; fm < 4; ++fm)
#pragma unroll
      for (int j = 0; j < 4; ++j) {
        const int t = wm * 64 + fm * 16 + kg4 * 4 + j;
#pragma unroll
        for (int fn = 0; fn < 4; ++fn) {
          const int d = fn * 32 + wn * 16 + l15;
          svt[d * 136 + t] = (bf16_t)(qc[fm][fn][j] * svl[fm][j]);
        }
        if (wn == 0 && l15 == 0) {
          const float nq2 = nq2_[fm][j] + s_red[1][t][2];
          a2vp[(size_t)bh * Ss + ((bm + t) & (Ss - 1))] =
              svl[fm][j] * sqrtf(nq2) / sqrtf(n2c[fm][j]);
        }
      }
    __syncthreads();
    const int d = tid >> 1, toff = (tid & 1) * 64;
    const int s0 = bm & (Ss - 1);
    const bf16_t* src = svt + d * 136 + toff;
    bf16_t* dst = vdq + ((size_t)bh * Dh + d) * Ss + s0 + toff;
#pragma unroll
    for (int k = 0; k < 8; ++k) {
      bf16x8 tv;
#pragma unroll
      for (int e = 0; e < 8; ++e) tv[e] = src[k * 8 + e];
      *(bf16x8*)(dst + k * 8) = tv;
    }
  }
}

// ===== output i8 GEMM: BK=128 single-buffer 2-barrier core (best at 512 blocks) =====
__global__ __launch_bounds__(256) void gemm0_kernel(
    const int8_t* __restrict__ A, const float* __restrict__ sA,
    const int8_t* __restrict__ W, const float* __restrict__ sW,
    float* __restrict__ out, int M, int N, int K)
{
  __shared__ __align__(16) int8_t As[128 * 128];
  __shared__ __align__(16) int8_t Bs[128 * 128];
  const int tid = threadIdx.x, lane = tid & 63, wid = tid >> 6;
  const int id = blockIdx.x;
  const int xcd = id & 7, within = id >> 3;
  const int nIdx = xcd * 4 + (within >> 4);
  const int mIdx = within & 15;
  const int bm = mIdx * 128, bn = nIdx * 128;
  const int wm = wid >> 1, wn = wid & 1;
  const int l15 = lane & 15, kg4 = lane >> 4;

  const int strow = wid * 8 + (lane >> 3);
  const int schunk = ((lane & 7) ^ (lane >> 3)) * 16;
  const int8_t* gA = A + (size_t)(bm + strow) * K + schunk;
  const int8_t* gB = W + (size_t)(bn + strow) * K + schunk;

  i32x4 acc[4][4] = {};
  for (int k0 = 0; k0 < K; k0 += 128) {
    if (k0) __syncthreads();
#pragma unroll
    for (int r = 0; r < 4; ++r) {
      gload_lds16(gA + k0 + (size_t)r * 32 * K, As + r * 4096 + wid * 1024);
      gload_lds16(gB + k0 + (size_t)r * 32 * K, Bs + r * 4096 + wid * 1024);
    }
    __syncthreads();
#pragma unroll
    for (int g = 0; g < 2; ++g) {
      i32x4 af[4], bw[4];
#pragma unroll
      for (int f = 0; f < 4; ++f) {
        const int ca = (((g << 2) | kg4) ^ (l15 & 7)) * 16;
        af[f] = *(const i32x4*)&As[(wm * 64 + f * 16 + l15) * 128 + ca];
        bw[f] = *(const i32x4*)&Bs[(f * 32 + wn * 16 + l15) * 128 + ca];
      }
#pragma unroll
      for (int fm = 0; fm < 4; ++fm)
#pragma unroll
        for (int fn = 0; fn < 4; ++fn)
          acc[fm][fn] = __builtin_amdgcn_mfma_i32_16x16x64_i8(af[fm], bw[fn], acc[fm][fn], 0, 0, 0);
    }
  }
#pragma unroll
  for (int fm = 0; fm < 4; ++fm) {
#pragma unroll
    for (int j = 0; j < 4; ++j) {
      const int row = bm + wm * 64 + fm * 16 + kg4 * 4 + j;
      const float sa = sA[row];
#pragma unroll
      for (int fn = 0; fn < 4; ++fn) {
        const int col = bn + fn * 32 + wn * 16 + l15;
        out[(size_t)row * N + col] = (float)acc[fm][fn][j] * sa * sW[col];
      }
    }
  }
}

// ------------- fused attention: 1 wave per 32 q-rows, no LDS, no barriers -------------
// grid (Bh, 32); unit u = 31 - blockIdx.y (heavy-first); q0 = u*32; nt = u+1 k-tiles.
#define KR(r) (((r) & 3) + 8 * ((r) >> 2) + 4 * hi)
__global__ __launch_bounds__(64, 2) void attn_kernel(
    const int8_t* __restrict__ qq, const int8_t* __restrict__ kq,
    const bf16_t* __restrict__ vdqt,
    const float* __restrict__ Fq, const float* __restrict__ Fk,
    const float* __restrict__ A2v, float* __restrict__ oattn)
{
  const int bh = blockIdx.x, b = bh >> 5, h = bh & 31;
  const int lane = threadIdx.x & 63;
  const int l31 = lane & 31, hi = lane >> 5;
  const int u = 31 - (int)blockIdx.y;
  const int q0 = u * 32;
  const int nt = u + 1;
  const size_t bhS = (size_t)bh * Ss;

  const int8_t* qrow = qq + (bhS + q0 + l31) * Dh + hi * 16;
  i32x4 qf[4];
#pragma unroll
  for (int c = 0; c < 4; ++c) qf[c] = *(const i32x4*)(qrow + c * 32);
  const float fq = Fq[bhS + q0 + l31];
  const int qcol = q0 + l31;

  float m = NEG_INF_F;
  int t = 0;
  for (; t + 1 < nt; t += 2) {
    const int kb0 = t * 32, kb1 = kb0 + 32;
    const int8_t* kr0 = kq + (bhS + kb0 + l31) * Dh + hi * 16;
    const int8_t* kr1 = kq + (bhS + kb1 + l31) * Dh + hi * 16;
    i32x16 ca = {}, cb = {}, da = {}, db = {};
    ca = __builtin_amdgcn_mfma_i32_32x32x32_i8(*(const i32x4*)(kr0),      qf[0], ca, 0, 0, 0);
    cb = __builtin_amdgcn_mfma_i32_32x32x32_i8(*(const i32x4*)(kr0 + 64), qf[2], cb, 0, 0, 0);
    da = __builtin_amdgcn_mfma_i32_32x32x32_i8(*(const i32x4*)(kr1),      qf[0], da, 0, 0, 0);
    db = __builtin_amdgcn_mfma_i32_32x32x32_i8(*(const i32x4*)(kr1 + 64), qf[2], db, 0, 0, 0);
    ca = __builtin_amdgcn_mfma_i32_32x32x32_i8(*(const i32x4*)(kr0 + 32), qf[1], ca, 0, 0, 0);
    cb = __builtin_amdgcn_mfma_i32_32x32x32_i8(*(const i32x4*)(kr0 + 96), qf[3], cb, 0, 0, 0);
    da = __builtin_amdgcn_mfma_i32_32x32x32_i8(*(const i32x4*)(kr1 + 32), qf[1], da, 0, 0, 0);
    db = __builtin_amdgcn_mfma_i32_32x32x32_i8(*(const i32x4*)(kr1 + 96), qf[3], db, 0, 0, 0);
    float4 fk40[4], fk41[4];
#pragma unroll
    for (int g = 0; g < 4; ++g) fk40[g] = *(const float4*)&Fk[bhS + kb0 + g * 8 + 4 * hi];
#pragma unroll
    for (int g = 0; g < 4; ++g) fk41[g] = *(const float4*)&Fk[bhS + kb1 + g * 8 + 4 * hi];
    const bool diag1 = (t + 1 == nt - 1);
#pragma unroll
    for (int r = 0; r < 16; ++r) {
      m = fmaxf(m, (float)(ca[r] + cb[r]) * fq * ((const float*)&fk40[r >> 2])[r & 3]);
      const float v1 = (float)(da[r] + db[r]) * fq * ((const float*)&fk41[r >> 2])[r & 3];
      if (!diag1 || (kb1 + KR(r) <= qcol)) m = fmaxf(m, v1);
    }
  }
  if (t < nt) {
    const int kb = t * 32;
    const int8_t* krow = kq + (bhS + kb + l31) * Dh + hi * 16;
    i32x16 ca = {}, cb = {};
    ca = __builtin_amdgcn_mfma_i32_32x32x32_i8(*(const i32x4*)(krow),      qf[0], ca, 0, 0, 0);
    cb = __builtin_amdgcn_mfma_i32_32x32x32_i8(*(const i32x4*)(krow + 64), qf[2], cb, 0, 0, 0);
    ca = __builtin_amdgcn_mfma_i32_32x32x32_i8(*(const i32x4*)(krow + 32), qf[1], ca, 0, 0, 0);
    cb = __builtin_amdgcn_mfma_i32_32x32x32_i8(*(const i32x4*)(krow + 96), qf[3], cb, 0, 0, 0);
    float4 fk4[4];
#pragma unroll
    for (int g = 0; g < 4; ++g) fk4[g] = *(const float4*)&Fk[bhS + kb + g * 8 + 4 * hi];
#pragma unroll
    for (int r = 0; r < 16; ++r) {
      const float v = (float)(ca[r] + cb[r]) * fq * ((const float*)&fk4[r >> 2])[r & 3];
      if (kb + KR(r) <= qcol) m = fmaxf(m, v);
    }
  }
  m = fmaxf(m, __shfl_xor(m, 32));

  float z = 0.f;
  f32x16 oacc[4] = {};
  for (int tt = 0; tt < nt; ++tt) {
    const int kb = tt * 32;
    const int8_t* krow = kq + (bhS + kb + l31) * Dh + hi * 16;
    i32x16 ca = {}, cb = {};
    ca = __builtin_amdgcn_mfma_i32_32x32x32_i8(*(const i32x4*)(krow),      qf[0], ca, 0, 0, 0);
    cb = __builtin_amdgcn_mfma_i32_32x32x32_i8(*(const i32x4*)(krow + 64), qf[2], cb, 0, 0, 0);
    ca = __builtin_amdgcn_mfma_i32_32x32x32_i8(*(const i32x4*)(krow + 32), qf[1], ca, 0, 0, 0);
    cb = __builtin_amdgcn_mfma_i32_32x32x32_i8(*(const i32x4*)(krow + 96), qf[3], cb, 0, 0, 0);
    float4 fk4[4];
#pragma unroll
    for (int g = 0; g < 4; ++g) fk4[g] = *(const float4*)&Fk[bhS + kb + g * 8 + 4 * hi];
    float p[16];
    const bool diag = (tt == nt - 1);
#pragma unroll
    for (int r = 0; r < 16; ++r) {
      float v = (float)(ca[r] + cb[r]) * fq * ((const float*)&fk4[r >> 2])[r & 3];
      if (diag && (kb + KR(r) > qcol)) v = NEG_INF_F;
      const float e = __expf(v - m);
      z += e;
      p[r] = rintf(127.0f * e);
    }
#pragma unroll
    for (int s = 0; s < 2; ++s) {
      const int rs = s * 8;
      unsigned k0 = pkbf(p[rs + 0], p[rs + 1]);
      unsigned k1 = pkbf(p[rs + 2], p[rs + 3]);
      unsigned k2 = pkbf(p[rs + 4], p[rs + 5]);
      unsigned k3 = pkbf(p[rs + 6], p[rs + 7]);
      unsigned sx0 = __shfl_xor(k0, 32);
      unsigned sx1 = __shfl_xor(k1, 32);
      unsigned sx2 = __shfl_xor(k2, 32);
      unsigned sx3 = __shfl_xor(k3, 32);
      uint4 ww;
      ww.x = hi ? sx2 : k0;
      ww.y = hi ? sx3 : k1;
      ww.z = hi ? k2 : sx0;
      ww.w = hi ? k3 : sx1;
      const bf16x8 af = __builtin_bit_cast(bf16x8, ww);
      const int kg2 = kb + s * 16 + hi * 8;
#pragma unroll
      for (int dt = 0; dt < 4; ++dt) {
        const bf16x8 vf = *(const bf16x8*)(vdqt + ((size_t)bh * Dh + dt * 32 + l31) * Ss + kg2);
        oacc[dt] = __builtin_amdgcn_mfma_f32_32x32x16_bf16(af, vf, oacc[dt], 0, 0, 0);
      }
    }
  }
  z += __shfl_xor(z, 32);
  const float osc = (1.0f / z) / 127.0f / A2v[bhS + q0 + l31];
#pragma unroll
  for (int dt = 0; dt < 4; ++dt) {
#pragma unroll
    for (int r = 0; r < 16; ++r) {
      const int q = q0 + KR(r);
      const float oscr = __shfl(osc, KR(r));
      oattn[((size_t)b * Ss + q) * Hid + h * Dh + dt * 32 + l31] = oacc[dt][r] * oscr;
    }
  }
}

extern "C" void kernel_launch(void* const* d_in, const int* in_sizes, int n_in,
                              void* d_out, int out_size, void* d_ws, size_t ws_size,
                              hipStream_t stream)
{
  const float* hidden = (const float*)d_in[0];
  const float* wq = (const float*)d_in[1];
  const float* wk = (const float*)d_in[2];
  const float* wv = (const float*)d_in[3];
  const float* wo = (const float*)d_in[4];
  float* out = (float*)d_out;

  char* p = (char*)d_ws;
  auto alloc = [&](size_t bytes) -> char* {
    char* r = p; p += (bytes + 255) & ~(size_t)255; return r;
  };
  int8_t* xq   = (int8_t*)alloc((size_t)Mr * Hid);       // later reused for oq
  int8_t* wb0  = (int8_t*)alloc((size_t)Hid * Hid);      // wq codes; later wo codes
  int8_t* wb1  = (int8_t*)alloc((size_t)Hid * Hid);      // wk codes
  int8_t* wb2  = (int8_t*)alloc((size_t)Hid * Hid);      // wv codes
  float*  oat  = (float*) alloc((size_t)Bh * Ss * Dh * sizeof(float));
  int8_t* qqb  = (int8_t*)alloc((size_t)Bh * Ss * Dh);
  int8_t* kqb  = (int8_t*)alloc((size_t)Bh * Ss * Dh);
  bf16_t* vdqt = (bf16_t*)alloc((size_t)Bh * Dh * Ss * sizeof(bf16_t));
  float* sxa = (float*)alloc((size_t)Mr * sizeof(float));
  float* sw0 = (float*)alloc((size_t)Hid * sizeof(float));
  float* sw1 = (float*)alloc((size_t)Hid * sizeof(float));
  float* sw2 = (float*)alloc((size_t)Hid * sizeof(float));
  float* Fq  = (float*)alloc((size_t)Bh * Ss * sizeof(float));
  float* Fk  = (float*)alloc((size_t)Bh * Ss * sizeof(float));
  float* A2v = (float*)alloc((size_t)Bh * Ss * sizeof(float));
  float* soa = (float*)alloc((size_t)Mr * sizeof(float));
  float* ctab = (float*)alloc((size_t)Ss * 64 * sizeof(float));
  float* stab = (float*)alloc((size_t)Ss * 64 * sizeof(float));
  int8_t* oq  = xq;   // xq dead after QKV GEMM

  rope_table_kernel<<<Ss * 64 / 256, 256, 0, stream>>>(ctab, stab);
  quant_rows_kernel<<<Mr, 256, 0, stream>>>(hidden, xq, sxa, Hid, 127.f, -128.f, 127.f);
  quant_w3_kernel<<<3 * Hid, 256, 0, stream>>>(wq, wk, wv, wb0, wb1, wb2, sw0, sw1, sw2);

  qkv_gemm_kernel<<<1536, 256, 0, stream>>>(xq, sxa, wb0, wb1, wb2, sw0, sw1, sw2,
                                            qqb, Fq, kqb, Fk, vdqt, A2v, ctab, stab);

  dim3 ga(Bh, 32);
  attn_kernel<<<ga, 64, 0, stream>>>(qqb, kqb, vdqt, Fq, Fk, A2v, oat);

  quant_rows_kernel<<<Mr, 256, 0, stream>>>(oat, oq, soa, Hid, 127.f, -128.f, 127.f);
  quant_rows_kernel<<<Hid, 256, 0, stream>>>(wo, wb0, sw0, Hid, 7.f, -8.f, 7.f);
  gemm0_kernel<<<512, 256, 0, stream>>>(oq, soa, wb0, sw0, out, Mr, Hid, Hid);
}

// Round 17
// 366.541 us; speedup vs baseline: 1.3833x; 1.0257x over previous
//
#include <hip/hip_runtime.h>
#include <hip/hip_bf16.h>
#include <math.h>
#include <stdint.h>

#define NEG_INF_F (-3.4028234663852886e38f)

typedef __bf16 bf16_t;
typedef __bf16 bf16x8 __attribute__((ext_vector_type(8)));
typedef float f32x4 __attribute__((ext_vector_type(4)));
typedef float f32x16 __attribute__((ext_vector_type(16)));
typedef int i32x4 __attribute__((ext_vector_type(4)));
typedef int i32x16 __attribute__((ext_vector_type(16)));
typedef int8_t c8x4 __attribute__((ext_vector_type(4)));

static constexpr int Bb = 2, Ss = 1024, Hid = 4096, Nh = 32, Dh = 128;
static constexpr int Mr = Bb * Ss;   // 2048 token rows
static constexpr int Bh = Bb * Nh;   // 64 (batch*heads)

__device__ __forceinline__ void gload_lds16(const void* g, void* l) {
  __builtin_amdgcn_global_load_lds((const __attribute__((address_space(1))) void*)g,
                                   (__attribute__((address_space(3))) void*)l, 16, 0, 0);
}

__device__ __forceinline__ float wred_max(float v) {
#pragma unroll
  for (int off = 32; off > 0; off >>= 1) v = fmaxf(v, __shfl_xor(v, off));
  return v;
}

__device__ __forceinline__ unsigned pkbf(float a, float b) {
  unsigned short ua = __builtin_bit_cast(unsigned short, (bf16_t)a);
  unsigned short ub = __builtin_bit_cast(unsigned short, (bf16_t)b);
  return (unsigned)ua | ((unsigned)ub << 16);
}

// ---------------- RoPE cos/sin tables [S][64] ----------------
__global__ void rope_table_kernel(float* __restrict__ ctab, float* __restrict__ stab) {
  int i = blockIdx.x * 256 + threadIdx.x;   // 0 .. S*64-1
  int srow = i >> 6, d = i & 63;
  float invf = (float)pow(10000.0, -((double)(2 * d) / (double)Dh));
  float ang = (float)srow * invf;           // f32 mul like numpy outer()
  ctab[i] = (float)cos((double)ang);
  stab[i] = (float)sin((double)ang);
}

// ------------- per-row symmetric fake-quant: int8 codes + f32 scale -------------
__device__ __forceinline__ void quant_row_body(
    const float* __restrict__ x, int8_t* __restrict__ o, float* __restrict__ scale,
    int row, int ncols, float qmax, float clo, float chi)
{
  const int tid = threadIdx.x;
  const float4* x4 = (const float4*)x;
  const int n4 = ncols >> 2;
  float m = 0.f;
  for (int i = tid; i < n4; i += 256) {
    float4 v = x4[i];
    m = fmaxf(m, fmaxf(fmaxf(fabsf(v.x), fabsf(v.y)), fmaxf(fabsf(v.z), fabsf(v.w))));
  }
  m = wred_max(m);
  __shared__ float red[4];
  if ((tid & 63) == 0) red[tid >> 6] = m;
  __syncthreads();
  m = fmaxf(fmaxf(red[0], red[1]), fmaxf(red[2], red[3]));
  const float s = fmaxf(m / qmax, 1e-8f);
  if (tid == 0) scale[row] = s;
  c8x4* o4 = (c8x4*)o;
  for (int i = tid; i < n4; i += 256) {
    float4 v = x4[i];
    c8x4 r;
    r[0] = (int8_t)(int)fminf(fmaxf(rintf(v.x / s), clo), chi);
    r[1] = (int8_t)(int)fminf(fmaxf(rintf(v.y / s), clo), chi);
    r[2] = (int8_t)(int)fminf(fmaxf(rintf(v.z / s), clo), chi);
    r[3] = (int8_t)(int)fminf(fmaxf(rintf(v.w / s), clo), chi);
    o4[i] = r;
  }
}

__global__ __launch_bounds__(256) void quant_rows_kernel(
    const float* __restrict__ in, int8_t* __restrict__ outq,
    float* __restrict__ scale, int ncols, float qmax, float clo, float chi)
{
  const int row = blockIdx.x;
  quant_row_body(in + (size_t)row * ncols, outq + (size_t)row * ncols, scale,
                 row, ncols, qmax, clo, chi);
}

// 3 weights in one launch (w4 quant): sel = id>>12, row = id&4095
__global__ __launch_bounds__(256) void quant_w3_kernel(
    const float* __restrict__ w0, const float* __restrict__ w1, const float* __restrict__ w2,
    int8_t* __restrict__ o0, int8_t* __restrict__ o1, int8_t* __restrict__ o2,
    float* __restrict__ s0, float* __restrict__ s1, float* __restrict__ s2)
{
  const int sel = blockIdx.x >> 12, row = blockIdx.x & 4095;
  const float* in = sel == 0 ? w0 : (sel == 1 ? w1 : w2);
  int8_t* o = sel == 0 ? o0 : (sel == 1 ? o1 : o2);
  float* sc = sel == 0 ? s0 : (sel == 1 ? s1 : s2);
  quant_row_body(in + (size_t)row * Hid, o + (size_t)row * Hid, sc, row, Hid,
                 7.f, -8.f, 7.f);
}

// ================= fused QKV i8 GEMM, BK=128 single-buffer (measured-best global config) =================
// grid 1536; nIdx 0..95: wsel = nIdx>>5 (0:Q 1:K 2:V), head = nIdx&31.
// rows: bm + wm*64 + fm*16 + kg4*4 + j ; cols: bn + fn*32 + wn*16 + l15.
// Bank swizzle (128B rows): slot c of row r holds global chunk c^(r&7);
// source chunk (lane&7)^(lane>>3); read chunk ((g*4+kg4)^(l15&7)) -> 2-way (free).
__global__ __launch_bounds__(256) void qkv_gemm_kernel(
    const int8_t* __restrict__ A, const float* __restrict__ sA,
    const int8_t* __restrict__ wqz, const int8_t* __restrict__ wkz, const int8_t* __restrict__ wvz,
    const float* __restrict__ swq, const float* __restrict__ swk, const float* __restrict__ swv,
    int8_t* __restrict__ qqb, float* __restrict__ Fq,
    int8_t* __restrict__ kqb, float* __restrict__ Fk,
    bf16_t* __restrict__ vdq, float* __restrict__ a2vp,
    const float* __restrict__ ctab, const float* __restrict__ stab)
{
  __shared__ __align__(16) char smem[34816 + 3072];
  int8_t* As = (int8_t*)smem;
  int8_t* Bs = (int8_t*)(smem + 16384);
  float (*s_red)[128][3] = (float (*)[128][3])(smem + 34816);

  const int tid = threadIdx.x, lane = tid & 63, wid = tid >> 6;
  const int id = blockIdx.x;                 // 1536 blocks, 8 XCDs, 12 n-panels each
  const int xcd = id & 7, within = id >> 3;  // within 0..191
  const int nIdx = xcd * 12 + (within >> 4); // 0..95
  const int mIdx = within & 15;
  const int wsel = nIdx >> 5, head = nIdx & 31;
  const int bm = mIdx * 128, bn = head * 128;
  const int8_t* W = wsel == 0 ? wqz : (wsel == 1 ? wkz : wvz);
  const float* sW = wsel == 0 ? swq : (wsel == 1 ? swk : swv);
  constexpr int K = Hid;

  const int wm = wid >> 1, wn = wid & 1;
  const int l15 = lane & 15, kg4 = lane >> 4;

  const int strow = wid * 8 + (lane >> 3);
  const int schunk = ((lane & 7) ^ (lane >> 3)) * 16;
  const int8_t* gA = A + (size_t)(bm + strow) * K + schunk;
  const int8_t* gB = W + (size_t)(bn + strow) * K + schunk;

  i32x4 acc[4][4] = {};
  for (int k0 = 0; k0 < K; k0 += 128) {
    if (k0) __syncthreads();
#pragma unroll
    for (int r = 0; r < 4; ++r) {
      gload_lds16(gA + k0 + (size_t)r * 32 * K, As + r * 4096 + wid * 1024);
      gload_lds16(gB + k0 + (size_t)r * 32 * K, Bs + r * 4096 + wid * 1024);
    }
    __syncthreads();
#pragma unroll
    for (int g = 0; g < 2; ++g) {
      i32x4 af[4], bw[4];
#pragma unroll
      for (int f = 0; f < 4; ++f) {
        const int ca = (((g << 2) | kg4) ^ (l15 & 7)) * 16;
        af[f] = *(const i32x4*)&As[(wm * 64 + f * 16 + l15) * 128 + ca];
        bw[f] = *(const i32x4*)&Bs[(f * 32 + wn * 16 + l15) * 128 + ca];
      }
#pragma unroll
      for (int fm = 0; fm < 4; ++fm)
#pragma unroll
        for (int fn = 0; fn < 4; ++fn)
          acc[fm][fn] = __builtin_amdgcn_mfma_i32_16x16x64_i8(af[fm], bw[fn], acc[fm][fn], 0, 0, 0);
    }
  }

  float sav[4][4], swv_[4];
#pragma unroll
  for (int fm = 0; fm < 4; ++fm)
#pragma unroll
    for (int j = 0; j < 4; ++j) sav[fm][j] = sA[bm + wm * 64 + fm * 16 + kg4 * 4 + j];
#pragma unroll
  for (int fn = 0; fn < 4; ++fn) swv_[fn] = sW[bn + fn * 32 + wn * 16 + l15];

  float val[4][4][4];
#pragma unroll
  for (int fm = 0; fm < 4; ++fm)
#pragma unroll
    for (int fn = 0; fn < 4; ++fn)
#pragma unroll
      for (int j = 0; j < 4; ++j)
        val[fm][fn][j] = (float)acc[fm][fn][j] * sav[fm][j] * swv_[fn];

  const int b = bm >> 10;
  const int bh = b * Nh + head;
  float r_[4][4][4];
  if (wsel != 2) {   // Q or K: rope
    const int dmA = wn * 16 + l15, dmB = 32 + wn * 16 + l15;
#pragma unroll
    for (int fm = 0; fm < 4; ++fm)
#pragma unroll
      for (int j = 0; j < 4; ++j) {
        const int srow = (bm + wm * 64 + fm * 16 + kg4 * 4 + j) & (Ss - 1);
        const float cA = ctab[srow * 64 + dmA], cB = ctab[srow * 64 + dmB];
        const float sA_ = stab[srow * 64 + dmA], sB_ = stab[srow * 64 + dmB];
        r_[fm][0][j] = __fsub_rn(__fmul_rn(val[fm][0][j], cA), __fmul_rn(val[fm][2][j], sA_));
        r_[fm][1][j] = __fsub_rn(__fmul_rn(val[fm][1][j], cB), __fmul_rn(val[fm][3][j], sB_));
        r_[fm][2][j] = __fadd_rn(__fmul_rn(val[fm][2][j], cA), __fmul_rn(val[fm][0][j], sA_));
        r_[fm][3][j] = __fadd_rn(__fmul_rn(val[fm][3][j], cB), __fmul_rn(val[fm][1][j], sB_));
      }
  } else {
#pragma unroll
    for (int fm = 0; fm < 4; ++fm)
#pragma unroll
      for (int fn = 0; fn < 4; ++fn)
#pragma unroll
        for (int j = 0; j < 4; ++j) r_[fm][fn][j] = val[fm][fn][j];
  }
  // per-row (ma, n2): wave-half partial then cross-wn via s_red
  float ma_[4][4], n2_[4][4];
#pragma unroll
  for (int fm = 0; fm < 4; ++fm)
#pragma unroll
    for (int j = 0; j < 4; ++j) {
      float ma = 0.f, n2 = 0.f;
#pragma unroll
      for (int fn = 0; fn < 4; ++fn) {
        const float x = r_[fm][fn][j];
        ma = fmaxf(ma, fabsf(x));
        n2 += x * x;
      }
#pragma unroll
      for (int off = 1; off < 16; off <<= 1) {
        ma = fmaxf(ma, __shfl_xor(ma, off));
        n2 += __shfl_xor(n2, off);
      }
      ma_[fm][j] = ma;
      n2_[fm][j] = n2;
    }
  if (l15 == 0) {
#pragma unroll
    for (int fm = 0; fm < 4; ++fm)
#pragma unroll
      for (int j = 0; j < 4; ++j) {
        const int rl = wm * 64 + fm * 16 + kg4 * 4 + j;
        s_red[wn][rl][0] = ma_[fm][j];
        s_red[wn][rl][1] = n2_[fm][j];
      }
  }
  __syncthreads();   // also retires As/Bs for the vt reuse below
  float qc[4][4][4], svl[4][4], n2c[4][4], nq2_[4][4];
#pragma unroll
  for (int fm = 0; fm < 4; ++fm)
#pragma unroll
    for (int j = 0; j < 4; ++j) {
      const int rl = wm * 64 + fm * 16 + kg4 * 4 + j;
      const float ma = fmaxf(ma_[fm][j], s_red[wn ^ 1][rl][0]);
      const float n2 = n2_[fm][j] + s_red[wn ^ 1][rl][1];
      const float s = fmaxf(ma / 127.0f, 1e-8f);
      float nq2 = 0.f;
#pragma unroll
      for (int fn = 0; fn < 4; ++fn) {
        const float q = fminf(fmaxf(rintf(r_[fm][fn][j] / s), -128.f), 127.f);
        qc[fm][fn][j] = q;
        nq2 += q * q;
      }
#pragma unroll
      for (int off = 1; off < 16; off <<= 1) nq2 += __shfl_xor(nq2, off);
      svl[fm][j] = s;
      n2c[fm][j] = n2;
      nq2_[fm][j] = nq2;
    }
  __syncthreads();
  if (l15 == 0) {
#pragma unroll
    for (int fm = 0; fm < 4; ++fm)
#pragma unroll
      for (int j = 0; j < 4; ++j)
        s_red[wn][wm * 64 + fm * 16 + kg4 * 4 + j][2] = nq2_[fm][j];
  }
  __syncthreads();

  if (wsel != 2) {
    int8_t* outq = (wsel == 0) ? qqb : kqb;
    float* Ff = (wsel == 0) ? Fq : Fk;
#pragma unroll
    for (int fm = 0; fm < 4; ++fm)
#pragma unroll
      for (int j = 0; j < 4; ++j) {
        const int rl = wm * 64 + fm * 16 + kg4 * 4 + j;
        const int stok = (bm + rl) & (Ss - 1);
        const size_t rowBase = ((size_t)bh * Ss + stok) * Dh;
#pragma unroll
        for (int fn = 0; fn < 4; ++fn)
          outq[rowBase + fn * 32 + wn * 16 + l15] = (int8_t)(int)qc[fm][fn][j];
        if (wn == 0 && l15 == 0) {
          const float nq2 = nq2_[fm][j] + s_red[1][rl][2];
          Ff[(size_t)bh * Ss + stok] = sqrtf(n2c[fm][j] / nq2) * 0.2973017787506803f;
        }
      }
  } else {
    bf16_t* svt = (bf16_t*)smem;   // reuses As/Bs region (retired above)
#pragma unroll
    for (int fm = 0; fm < 4; ++fm)
#pragma unroll
      for (int j = 0; j < 4; ++j) {
        const int t = wm * 64 + fm * 16 + kg4 * 4 + j;
#pragma unroll
        for (int fn = 0; fn < 4; ++fn) {
          const int d = fn * 32 + wn * 16 + l15;
          svt[d * 136 + t] = (bf16_t)(qc[fm][fn][j] * svl[fm][j]);
        }
        if (wn == 0 && l15 == 0) {
          const float nq2 = nq2_[fm][j] + s_red[1][t][2];
          a2vp[(size_t)bh * Ss + ((bm + t) & (Ss - 1))] =
              svl[fm][j] * sqrtf(nq2) / sqrtf(n2c[fm][j]);
        }
      }
    __syncthreads();
    const int d = tid >> 1, toff = (tid & 1) * 64;
    const int s0 = bm & (Ss - 1);
    const bf16_t* src = svt + d * 136 + toff;
    bf16_t* dst = vdq + ((size_t)bh * Dh + d) * Ss + s0 + toff;
#pragma unroll
    for (int k = 0; k < 8; ++k) {
      bf16x8 tv;
#pragma unroll
      for (int e = 0; e < 8; ++e) tv[e] = src[k * 8 + e];
      *(bf16x8*)(dst + k * 8) = tv;
    }
  }
}

// ===== output i8 GEMM: BK=128 single-buffer 2-barrier core (best at 512 blocks) =====
__global__ __launch_bounds__(256) void gemm0_kernel(
    const int8_t* __restrict__ A, const float* __restrict__ sA,
    const int8_t* __restrict__ W, const float* __restrict__ sW,
    float* __restrict__ out, int M, int N, int K)
{
  __shared__ __align__(16) int8_t As[128 * 128];
  __shared__ __align__(16) int8_t Bs[128 * 128];
  const int tid = threadIdx.x, lane = tid & 63, wid = tid >> 6;
  const int id = blockIdx.x;
  const int xcd = id & 7, within = id >> 3;
  const int nIdx = xcd * 4 + (within >> 4);
  const int mIdx = within & 15;
  const int bm = mIdx * 128, bn = nIdx * 128;
  const int wm = wid >> 1, wn = wid & 1;
  const int l15 = lane & 15, kg4 = lane >> 4;

  const int strow = wid * 8 + (lane >> 3);
  const int schunk = ((lane & 7) ^ (lane >> 3)) * 16;
  const int8_t* gA = A + (size_t)(bm + strow) * K + schunk;
  const int8_t* gB = W + (size_t)(bn + strow) * K + schunk;

  i32x4 acc[4][4] = {};
  for (int k0 = 0; k0 < K; k0 += 128) {
    if (k0) __syncthreads();
#pragma unroll
    for (int r = 0; r < 4; ++r) {
      gload_lds16(gA + k0 + (size_t)r * 32 * K, As + r * 4096 + wid * 1024);
      gload_lds16(gB + k0 + (size_t)r * 32 * K, Bs + r * 4096 + wid * 1024);
    }
    __syncthreads();
#pragma unroll
    for (int g = 0; g < 2; ++g) {
      i32x4 af[4], bw[4];
#pragma unroll
      for (int f = 0; f < 4; ++f) {
        const int ca = (((g << 2) | kg4) ^ (l15 & 7)) * 16;
        af[f] = *(const i32x4*)&As[(wm * 64 + f * 16 + l15) * 128 + ca];
        bw[f] = *(const i32x4*)&Bs[(f * 32 + wn * 16 + l15) * 128 + ca];
      }
#pragma unroll
      for (int fm = 0; fm < 4; ++fm)
#pragma unroll
        for (int fn = 0; fn < 4; ++fn)
          acc[fm][fn] = __builtin_amdgcn_mfma_i32_16x16x64_i8(af[fm], bw[fn], acc[fm][fn], 0, 0, 0);
    }
  }
#pragma unroll
  for (int fm = 0; fm < 4; ++fm) {
#pragma unroll
    for (int j = 0; j < 4; ++j) {
      const int row = bm + wm * 64 + fm * 16 + kg4 * 4 + j;
      const float sa = sA[row];
#pragma unroll
      for (int fn = 0; fn < 4; ++fn) {
        const int col = bn + fn * 32 + wn * 16 + l15;
        out[(size_t)row * N + col] = (float)acc[fm][fn][j] * sa * sW[col];
      }
    }
  }
}

// ------------- fused attention: 1 wave per 32 q-rows, no LDS, no barriers -------------
// grid (Bh, 32); unit u = 31 - blockIdx.y (heavy-first); q0 = u*32; nt = u+1 k-tiles.
#define KR(r) (((r) & 3) + 8 * ((r) >> 2) + 4 * hi)
__global__ __launch_bounds__(64, 2) void attn_kernel(
    const int8_t* __restrict__ qq, const int8_t* __restrict__ kq,
    const bf16_t* __restrict__ vdqt,
    const float* __restrict__ Fq, const float* __restrict__ Fk,
    const float* __restrict__ A2v, float* __restrict__ oattn)
{
  const int bh = blockIdx.x, b = bh >> 5, h = bh & 31;
  const int lane = threadIdx.x & 63;
  const int l31 = lane & 31, hi = lane >> 5;
  const int u = 31 - (int)blockIdx.y;
  const int q0 = u * 32;
  const int nt = u + 1;
  const size_t bhS = (size_t)bh * Ss;

  const int8_t* qrow = qq + (bhS + q0 + l31) * Dh + hi * 16;
  i32x4 qf[4];
#pragma unroll
  for (int c = 0; c < 4; ++c) qf[c] = *(const i32x4*)(qrow + c * 32);
  const float fq = Fq[bhS + q0 + l31];
  const int qcol = q0 + l31;

  float m = NEG_INF_F;
  int t = 0;
  for (; t + 1 < nt; t += 2) {
    const int kb0 = t * 32, kb1 = kb0 + 32;
    const int8_t* kr0 = kq + (bhS + kb0 + l31) * Dh + hi * 16;
    const int8_t* kr1 = kq + (bhS + kb1 + l31) * Dh + hi * 16;
    i32x16 ca = {}, cb = {}, da = {}, db = {};
    ca = __builtin_amdgcn_mfma_i32_32x32x32_i8(*(const i32x4*)(kr0),      qf[0], ca, 0, 0, 0);
    cb = __builtin_amdgcn_mfma_i32_32x32x32_i8(*(const i32x4*)(kr0 + 64), qf[2], cb, 0, 0, 0);
    da = __builtin_amdgcn_mfma_i32_32x32x32_i8(*(const i32x4*)(kr1),      qf[0], da, 0, 0, 0);
    db = __builtin_amdgcn_mfma_i32_32x32x32_i8(*(const i32x4*)(kr1 + 64), qf[2], db, 0, 0, 0);
    ca = __builtin_amdgcn_mfma_i32_32x32x32_i8(*(const i32x4*)(kr0 + 32), qf[1], ca, 0, 0, 0);
    cb = __builtin_amdgcn_mfma_i32_32x32x32_i8(*(const i32x4*)(kr0 + 96), qf[3], cb, 0, 0, 0);
    da = __builtin_amdgcn_mfma_i32_32x32x32_i8(*(const i32x4*)(kr1 + 32), qf[1], da, 0, 0, 0);
    db = __builtin_amdgcn_mfma_i32_32x32x32_i8(*(const i32x4*)(kr1 + 96), qf[3], db, 0, 0, 0);
    float4 fk40[4], fk41[4];
#pragma unroll
    for (int g = 0; g < 4; ++g) fk40[g] = *(const float4*)&Fk[bhS + kb0 + g * 8 + 4 * hi];
#pragma unroll
    for (int g = 0; g < 4; ++g) fk41[g] = *(const float4*)&Fk[bhS + kb1 + g * 8 + 4 * hi];
    const bool diag1 = (t + 1 == nt - 1);
#pragma unroll
    for (int r = 0; r < 16; ++r) {
      m = fmaxf(m, (float)(ca[r] + cb[r]) * fq * ((const float*)&fk40[r >> 2])[r & 3]);
      const float v1 = (float)(da[r] + db[r]) * fq * ((const float*)&fk41[r >> 2])[r & 3];
      if (!diag1 || (kb1 + KR(r) <= qcol)) m = fmaxf(m, v1);
    }
  }
  if (t < nt) {
    const int kb = t * 32;
    const int8_t* krow = kq + (bhS + kb + l31) * Dh + hi * 16;
    i32x16 ca = {}, cb = {};
    ca = __builtin_amdgcn_mfma_i32_32x32x32_i8(*(const i32x4*)(krow),      qf[0], ca, 0, 0, 0);
    cb = __builtin_amdgcn_mfma_i32_32x32x32_i8(*(const i32x4*)(krow + 64), qf[2], cb, 0, 0, 0);
    ca = __builtin_amdgcn_mfma_i32_32x32x32_i8(*(const i32x4*)(krow + 32), qf[1], ca, 0, 0, 0);
    cb = __builtin_amdgcn_mfma_i32_32x32x32_i8(*(const i32x4*)(krow + 96), qf[3], cb, 0, 0, 0);
    float4 fk4[4];
#pragma unroll
    for (int g = 0; g < 4; ++g) fk4[g] = *(const float4*)&Fk[bhS + kb + g * 8 + 4 * hi];
#pragma unroll
    for (int r = 0; r < 16; ++r) {
      const float v = (float)(ca[r] + cb[r]) * fq * ((const float*)&fk4[r >> 2])[r & 3];
      if (kb + KR(r) <= qcol) m = fmaxf(m, v);
    }
  }
  m = fmaxf(m, __shfl_xor(m, 32));

  float z = 0.f;
  f32x16 oacc[4] = {};
  for (int tt = 0; tt < nt; ++tt) {
    const int kb = tt * 32;
    const int8_t* krow = kq + (bhS + kb + l31) * Dh + hi * 16;
    i32x16 ca = {}, cb = {};
    ca = __builtin_amdgcn_mfma_i32_32x32x32_i8(*(const i32x4*)(krow),      qf[0], ca, 0, 0, 0);
    cb = __builtin_amdgcn_mfma_i32_32x32x32_i8(*(const i32x4*)(krow + 64), qf[2], cb, 0, 0, 0);
    ca = __builtin_amdgcn_mfma_i32_32x32x32_i8(*(const i32x4*)(krow + 32), qf[1], ca, 0, 0, 0);
    cb = __builtin_amdgcn_mfma_i32_32x32x32_i8(*(const i32x4*)(krow + 96), qf[3], cb, 0, 0, 0);
    float4 fk4[4];
#pragma unroll
    for (int g = 0; g < 4; ++g) fk4[g] = *(const float4*)&Fk[bhS + kb + g * 8 + 4 * hi];
    float p[16];
    const bool diag = (tt == nt - 1);
#pragma unroll
    for (int r = 0; r < 16; ++r) {
      float v = (float)(ca[r] + cb[r]) * fq * ((const float*)&fk4[r >> 2])[r & 3];
      if (diag && (kb + KR(r) > qcol)) v = NEG_INF_F;
      const float e = __expf(v - m);
      z += e;
      p[r] = rintf(127.0f * e);
    }
#pragma unroll
    for (int s = 0; s < 2; ++s) {
      const int rs = s * 8;
      unsigned k0 = pkbf(p[rs + 0], p[rs + 1]);
      unsigned k1 = pkbf(p[rs + 2], p[rs + 3]);
      unsigned k2 = pkbf(p[rs + 4], p[rs + 5]);
      unsigned k3 = pkbf(p[rs + 6], p[rs + 7]);
      unsigned sx0 = __shfl_xor(k0, 32);
      unsigned sx1 = __shfl_xor(k1, 32);
      unsigned sx2 = __shfl_xor(k2, 32);
      unsigned sx3 = __shfl_xor(k3, 32);
      uint4 ww;
      ww.x = hi ? sx2 : k0;
      ww.y = hi ? sx3 : k1;
      ww.z = hi ? k2 : sx0;
      ww.w = hi ? k3 : sx1;
      const bf16x8 af = __builtin_bit_cast(bf16x8, ww);
      const int kg2 = kb + s * 16 + hi * 8;
#pragma unroll
      for (int dt = 0; dt < 4; ++dt) {
        const bf16x8 vf = *(const bf16x8*)(vdqt + ((size_t)bh * Dh + dt * 32 + l31) * Ss + kg2);
        oacc[dt] = __builtin_amdgcn_mfma_f32_32x32x16_bf16(af, vf, oacc[dt], 0, 0, 0);
      }
    }
  }
  z += __shfl_xor(z, 32);
  const float osc = (1.0f / z) / 127.0f / A2v[bhS + q0 + l31];
#pragma unroll
  for (int dt = 0; dt < 4; ++dt) {
#pragma unroll
    for (int r = 0; r < 16; ++r) {
      const int q = q0 + KR(r);
      const float oscr = __shfl(osc, KR(r));
      oattn[((size_t)b * Ss + q) * Hid + h * Dh + dt * 32 + l31] = oacc[dt][r] * oscr;
    }
  }
}

extern "C" void kernel_launch(void* const* d_in, const int* in_sizes, int n_in,
                              void* d_out, int out_size, void* d_ws, size_t ws_size,
                              hipStream_t stream)
{
  const float* hidden = (const float*)d_in[0];
  const float* wq = (const float*)d_in[1];
  const float* wk = (const float*)d_in[2];
  const float* wv = (const float*)d_in[3];
  const float* wo = (const float*)d_in[4];
  float* out = (float*)d_out;

  char* p = (char*)d_ws;
  auto alloc = [&](size_t bytes) -> char* {
    char* r = p; p += (bytes + 255) & ~(size_t)255; return r;
  };
  int8_t* xq   = (int8_t*)alloc((size_t)Mr * Hid);       // later reused for oq
  int8_t* wb0  = (int8_t*)alloc((size_t)Hid * Hid);      // wq codes; later wo codes
  int8_t* wb1  = (int8_t*)alloc((size_t)Hid * Hid);      // wk codes
  int8_t* wb2  = (int8_t*)alloc((size_t)Hid * Hid);      // wv codes
  float*  oat  = (float*) alloc((size_t)Bh * Ss * Dh * sizeof(float));
  int8_t* qqb  = (int8_t*)alloc((size_t)Bh * Ss * Dh);
  int8_t* kqb  = (int8_t*)alloc((size_t)Bh * Ss * Dh);
  bf16_t* vdqt = (bf16_t*)alloc((size_t)Bh * Dh * Ss * sizeof(bf16_t));
  float* sxa = (float*)alloc((size_t)Mr * sizeof(float));
  float* sw0 = (float*)alloc((size_t)Hid * sizeof(float));
  float* sw1 = (float*)alloc((size_t)Hid * sizeof(float));
  float* sw2 = (float*)alloc((size_t)Hid * sizeof(float));
  float* Fq  = (float*)alloc((size_t)Bh * Ss * sizeof(float));
  float* Fk  = (float*)alloc((size_t)Bh * Ss * sizeof(float));
  float* A2v = (float*)alloc((size_t)Bh * Ss * sizeof(float));
  float* soa = (float*)alloc((size_t)Mr * sizeof(float));
  float* ctab = (float*)alloc((size_t)Ss * 64 * sizeof(float));
  float* stab = (float*)alloc((size_t)Ss * 64 * sizeof(float));
  int8_t* oq  = xq;   // xq dead after QKV GEMM

  rope_table_kernel<<<Ss * 64 / 256, 256, 0, stream>>>(ctab, stab);
  quant_rows_kernel<<<Mr, 256, 0, stream>>>(hidden, xq, sxa, Hid, 127.f, -128.f, 127.f);
  quant_w3_kernel<<<3 * Hid, 256, 0, stream>>>(wq, wk, wv, wb0, wb1, wb2, sw0, sw1, sw2);

  qkv_gemm_kernel<<<1536, 256, 0, stream>>>(xq, sxa, wb0, wb1, wb2, sw0, sw1, sw2,
                                            qqb, Fq, kqb, Fk, vdqt, A2v, ctab, stab);

  dim3 ga(Bh, 32);
  attn_kernel<<<ga, 64, 0, stream>>>(qqb, kqb, vdqt, Fq, Fk, A2v, oat);

  quant_rows_kernel<<<Mr, 256, 0, stream>>>(oat, oq, soa, Hid, 127.f, -128.f, 127.f);
  quant_rows_kernel<<<Hid, 256, 0, stream>>>(wo, wb0, sw0, Hid, 7.f, -8.f, 7.f);
  gemm0_kernel<<<512, 256, 0, stream>>>(oq, soa, wb0, sw0, out, Mr, Hid, Hid);
}